// Round 1
// baseline (14063.443 us; speedup 1.0000x reference)
//
#include <hip/hip_runtime.h>
#include <hip/hip_bf16.h>
#include <math.h>

// DeepSeek V2 MLA attention, fp32 baseline.
// B=1 S=2048 E=2048 H=16 DN=128 DR=64 DV=128 R=512 QLR=1536
// Restructure: y = (attn@ckv) @ w_uv @ w_o  (avoids materializing w_o_abs).

#define EPS 1e-6f

// ---------------- block reduction helpers ----------------
__device__ __forceinline__ float block_sum(float v, float* red) {
#pragma unroll
  for (int off = 32; off > 0; off >>= 1) v += __shfl_down(v, off);
  const int lane = threadIdx.x & 63, w = threadIdx.x >> 6;
  if (lane == 0) red[w] = v;
  __syncthreads();
  float r = red[0];
  const int nw = (int)(blockDim.x >> 6);
  for (int i = 1; i < nw; ++i) r += red[i];
  __syncthreads();
  return r;
}

__device__ __forceinline__ float block_max(float v, float* red) {
#pragma unroll
  for (int off = 32; off > 0; off >>= 1) v = fmaxf(v, __shfl_down(v, off));
  const int lane = threadIdx.x & 63, w = threadIdx.x >> 6;
  if (lane == 0) red[w] = v;
  __syncthreads();
  float r = red[0];
  const int nw = (int)(blockDim.x >> 6);
  for (int i = 1; i < nw; ++i) r = fmaxf(r, red[i]);
  __syncthreads();
  return r;
}

// ---------------- generic tiled fp32 GEMM ----------------
// C[M,N] = A[M,K] @ (BT ? B[N,K]^T : B[K,N]); batched over blockIdx.z with
// element strides sA/sB/sC. All of M,N divisible by 64; K divisible by 16.
template<bool BT>
__global__ __launch_bounds__(256) void gemm_f32(
    const float* __restrict__ A, const float* __restrict__ B, float* __restrict__ C,
    int M, int N, int K, int lda, int ldb, int ldc,
    long sA, long sB, long sC)
{
  A += (long)blockIdx.z * sA;
  B += (long)blockIdx.z * sB;
  C += (long)blockIdx.z * sC;
  const int tid = threadIdx.x;
  const int m0 = blockIdx.y * 64, n0 = blockIdx.x * 64;
  __shared__ float As[16][65];
  __shared__ float Bs[16][65];
  const int ty = tid >> 4, tx = tid & 15;
  float acc[4][4] = {};
  for (int k0 = 0; k0 < K; k0 += 16) {
    {
      int row = tid >> 2, c4 = (tid & 3) << 2;
      const float4 v = *(const float4*)(A + (long)(m0 + row) * lda + k0 + c4);
      As[c4 + 0][row] = v.x; As[c4 + 1][row] = v.y;
      As[c4 + 2][row] = v.z; As[c4 + 3][row] = v.w;
    }
    if (BT) {
      int row = tid >> 2, c4 = (tid & 3) << 2;
      const float4 v = *(const float4*)(B + (long)(n0 + row) * ldb + k0 + c4);
      Bs[c4 + 0][row] = v.x; Bs[c4 + 1][row] = v.y;
      Bs[c4 + 2][row] = v.z; Bs[c4 + 3][row] = v.w;
    } else {
      int row = tid >> 4, c4 = (tid & 15) << 2;
      const float4 v = *(const float4*)(B + (long)(k0 + row) * ldb + n0 + c4);
      Bs[row][c4 + 0] = v.x; Bs[row][c4 + 1] = v.y;
      Bs[row][c4 + 2] = v.z; Bs[row][c4 + 3] = v.w;
    }
    __syncthreads();
#pragma unroll
    for (int k = 0; k < 16; ++k) {
      float a[4], b[4];
#pragma unroll
      for (int j = 0; j < 4; ++j) a[j] = As[k][ty * 4 + j];
#pragma unroll
      for (int j = 0; j < 4; ++j) b[j] = Bs[k][tx * 4 + j];
#pragma unroll
      for (int i = 0; i < 4; ++i)
#pragma unroll
        for (int j = 0; j < 4; ++j) acc[i][j] = fmaf(a[i], b[j], acc[i][j]);
    }
    __syncthreads();
  }
#pragma unroll
  for (int i = 0; i < 4; ++i)
#pragma unroll
    for (int j = 0; j < 4; ++j)
      C[(long)(m0 + ty * 4 + i) * ldc + n0 + tx * 4 + j] = acc[i][j];
}

// ---------------- RMSNorm (in place, one block per row) ----------------
__global__ __launch_bounds__(256) void rmsnorm_rows(float* x, const float* __restrict__ w, int n) {
  __shared__ float red[4];
  float* row = x + (long)blockIdx.x * n;
  float ss = 0.f;
  for (int i = threadIdx.x; i < n; i += 256) { float v = row[i]; ss += v * v; }
  float tot = block_sum(ss, red);
  float inv = rsqrtf(tot / (float)n + EPS);
  for (int i = threadIdx.x; i < n; i += 256) row[i] = row[i] * inv * w[i];
}

// ---------------- RoPE cos/sin table (double precision, 2048 x 32 each) ----
__global__ void rope_table(float* tab) {
  int s = blockIdx.x, j = threadIdx.x;  // 32 threads
  double freq = pow(10000.0, -(double)j / 32.0);
  double ang = (double)s * freq;
  tab[s * 64 + j] = (float)cos(ang);
  tab[s * 64 + 32 + j] = (float)sin(ang);
}

// ---------------- k_full: rmsnorm(ckv) ++ rope(k_pe) ----------------
__global__ __launch_bounds__(256) void build_kfull(const float* __restrict__ ckv,
                                                   const float* __restrict__ lnw,
                                                   const float* __restrict__ tab,
                                                   float* __restrict__ kf) {
  __shared__ float red[4];
  const int s = blockIdx.x;
  const float* row = ckv + (long)s * 576;
  float ss = 0.f;
  for (int i = threadIdx.x; i < 512; i += 256) { float v = row[i]; ss += v * v; }
  float tot = block_sum(ss, red);
  float inv = rsqrtf(tot / 512.0f + EPS);
  float* out = kf + (long)s * 576;
  for (int i = threadIdx.x; i < 512; i += 256) out[i] = row[i] * inv * lnw[i];
  if (threadIdx.x < 64) {
    int i = threadIdx.x, j = i & 31;
    float c = tab[s * 64 + j], sn = tab[s * 64 + 32 + j];
    float xv = row[512 + i];
    float rot = (i < 32) ? -row[512 + i + 32] : row[512 + i - 32];
    out[512 + i] = xv * c + rot * sn;
  }
}

// ---------------- roped q_pe into q_full[..., 512:576] ----------------
__global__ void rope_qpe(const float* __restrict__ q, const float* __restrict__ tab,
                         float* __restrict__ qf) {
  int s = blockIdx.x, h = blockIdx.y, i = threadIdx.x;  // 64 threads
  int j = i & 31;
  float c = tab[s * 64 + j], sn = tab[s * 64 + 32 + j];
  const float* src = q + (long)s * 3072 + h * 192 + 128;
  float xv = src[i];
  float rot = (i < 32) ? -src[i + 32] : src[i - 32];
  qf[(long)s * 9216 + h * 576 + 512 + i] = xv * c + rot * sn;
}

// ---------------- attention: one block per (q-row, head) ----------------
// scores in LDS (<=2048), softmax, o = p@ckv, epilogue o_v = o @ w_uv[h].
__global__ __launch_bounds__(256) void attn_fwd(const float* __restrict__ qf,
                                                const float* __restrict__ kf,
                                                const float* __restrict__ wkvb,
                                                float* __restrict__ ov_out) {
  __shared__ __align__(16) float qv[576];  // reused as o[512] in epilogue
  __shared__ float sc[2048];
  __shared__ float red[4];
  const int s = blockIdx.x, h = blockIdx.y, tid = threadIdx.x;
  const int L = s + 1;
  const float scale = 0.07216878364870323f;  // (DN+DR)^-0.5

  for (int i = tid; i < 576; i += 256) qv[i] = qf[(long)s * 9216 + h * 576 + i];
  __syncthreads();

  float lmax = -INFINITY;
  for (int k = tid; k < L; k += 256) {
    const float4* kr = (const float4*)(kf + (long)k * 576);
    const float4* qr = (const float4*)qv;
    float acc = 0.f;
#pragma unroll 4
    for (int i = 0; i < 144; ++i) {
      float4 a = qr[i], b = kr[i];
      acc += a.x * b.x + a.y * b.y + a.z * b.z + a.w * b.w;
    }
    float sv = acc * scale;
    sc[k] = sv;
    lmax = fmaxf(lmax, sv);
  }
  float gmax = block_max(lmax, red);

  float lsum = 0.f;
  for (int k = tid; k < L; k += 256) {
    float p = __expf(sc[k] - gmax);
    sc[k] = p;
    lsum += p;
  }
  float inv = 1.0f / block_sum(lsum, red);  // internal syncs make sc[] visible

  // o accumulation: thread t owns ckv dims 2t, 2t+1
  float o0 = 0.f, o1 = 0.f;
  const float* kc = kf + 2 * tid;
  for (int k = 0; k < L; ++k) {
    float p = sc[k];
    float2 c = *(const float2*)(kc + (long)k * 576);
    o0 = fmaf(p, c.x, o0);
    o1 = fmaf(p, c.y, o1);
  }
  __syncthreads();
  qv[2 * tid] = o0 * inv;
  qv[2 * tid + 1] = o1 * inv;
  __syncthreads();

  // epilogue: o_v[s, h*128+d] = sum_r o[r] * w_uv[r,h,d]
  if (tid < 128) {
    const float* wv = wkvb + h * 256 + 128 + tid;
    float acc = 0.f;
#pragma unroll 4
    for (int r = 0; r < 512; ++r) acc = fmaf(qv[r], wv[(long)r * 4096], acc);
    ov_out[(long)s * 2048 + h * 128 + tid] = acc;
  }
}

extern "C" void kernel_launch(void* const* d_in, const int* in_sizes, int n_in,
                              void* d_out, int out_size, void* d_ws, size_t ws_size,
                              hipStream_t stream) {
  const float* x      = (const float*)d_in[0];
  const float* w_q_a  = (const float*)d_in[1];
  const float* q_ln   = (const float*)d_in[2];
  const float* w_q_b  = (const float*)d_in[3];
  const float* w_kv_a = (const float*)d_in[4];
  const float* kv_ln  = (const float*)d_in[5];
  const float* w_kv_b = (const float*)d_in[6];
  const float* w_o    = (const float*)d_in[7];
  float* out = (float*)d_out;
  float* ws  = (float*)d_ws;

  // workspace layout (floats), with lifetime-based aliasing:
  float* qa  = ws;                 // 2048*1536 = 3145728   (later aliased by ckv)
  float* q   = qa + 3145728;       // 2048*3072 = 6291456   (later aliased by o_v)
  float* kf  = q + 6291456;        // 2048*576  = 1179648
  float* qf  = kf + 1179648;       // 2048*16*576 = 18874368
  float* tab = qf + 18874368;      // 2048*64   = 131072
  float* ckv = qa;                 // alias: qa dead once q is built
  float* o_v = q;                  // alias: q dead once q_full is built

  rope_table<<<dim3(2048), dim3(32), 0, stream>>>(tab);

  // q_a = x @ w_q_a ; rmsnorm
  gemm_f32<false><<<dim3(1536 / 64, 2048 / 64), 256, 0, stream>>>(
      x, w_q_a, qa, 2048, 1536, 2048, 2048, 1536, 1536, 0, 0, 0);
  rmsnorm_rows<<<2048, 256, 0, stream>>>(qa, q_ln, 1536);

  // q = q_a @ w_q_b
  gemm_f32<false><<<dim3(3072 / 64, 2048 / 64), 256, 0, stream>>>(
      qa, w_q_b, q, 2048, 3072, 1536, 1536, 3072, 3072, 0, 0, 0);

  // ckv_kpe = x @ w_kv_a (into qa region); k_full = rmsnorm ++ rope
  gemm_f32<false><<<dim3(576 / 64, 2048 / 64), 256, 0, stream>>>(
      x, w_kv_a, ckv, 2048, 576, 2048, 2048, 576, 576, 0, 0, 0);
  build_kfull<<<2048, 256, 0, stream>>>(ckv, kv_ln, tab, kf);

  // q_full[:, h, :512] = q_nope[h] @ w_uk[h]^T   (batched over h, B transposed)
  gemm_f32<true><<<dim3(512 / 64, 2048 / 64, 16), 256, 0, stream>>>(
      q, w_kv_b, qf, 2048, 512, 128, 3072, 4096, 9216, 192, 256, 576);
  // q_full[:, h, 512:] = rope(q_pe)
  rope_qpe<<<dim3(2048, 16), 64, 0, stream>>>(q, tab, qf);

  // attention + fused w_uv projection -> o_v (2048 x 2048)
  attn_fwd<<<dim3(2048, 16), 256, 0, stream>>>(qf, kf, w_kv_b, o_v);

  // y = o_v @ w_o
  gemm_f32<false><<<dim3(2048 / 64, 2048 / 64), 256, 0, stream>>>(
      o_v, w_o, out, 2048, 2048, 2048, 2048, 2048, 2048, 0, 0, 0);
}

// Round 2
// 5368.118 us; speedup vs baseline: 2.6198x; 2.6198x over previous
//
#include <hip/hip_runtime.h>
#include <hip/hip_bf16.h>
#include <math.h>

// DeepSeek V2 MLA attention, fp32, GEMM-structured attention.
// B=1 S=2048 E=2048 H=16 DN=128 DR=64 DV=128 R=512 QLR=1536
// y = softmax(mask(q_full@k_full^T)) @ (ckv@w_uv) @ w_o  per head.

#define EPS 1e-6f

// ---------------- block reduction helpers ----------------
__device__ __forceinline__ float block_sum(float v, float* red) {
#pragma unroll
  for (int off = 32; off > 0; off >>= 1) v += __shfl_down(v, off);
  const int lane = threadIdx.x & 63, w = threadIdx.x >> 6;
  if (lane == 0) red[w] = v;
  __syncthreads();
  float r = red[0];
  const int nw = (int)(blockDim.x >> 6);
  for (int i = 1; i < nw; ++i) r += red[i];
  __syncthreads();
  return r;
}

__device__ __forceinline__ float block_max(float v, float* red) {
#pragma unroll
  for (int off = 32; off > 0; off >>= 1) v = fmaxf(v, __shfl_down(v, off));
  const int lane = threadIdx.x & 63, w = threadIdx.x >> 6;
  if (lane == 0) red[w] = v;
  __syncthreads();
  float r = red[0];
  const int nw = (int)(blockDim.x >> 6);
  for (int i = 1; i < nw; ++i) r = fmaxf(r, red[i]);
  __syncthreads();
  return r;
}

// ---------------- generic tiled fp32 GEMM ----------------
// C[M,N] = A[M,K] @ (BT ? B[N,K]^T : B[K,N]); batched over blockIdx.z with
// element strides sA/sB/sC. M,N divisible by 64; K divisible by 16.
// mode: 0 = plain; 1 = causal block-skip (square 64-blocked scores: skip
// blocks with n0 > m0+63); 2 = causal K-cap (A cols beyond m0+63 are zero).
template<bool BT>
__global__ __launch_bounds__(256) void gemm_f32(
    const float* __restrict__ A, const float* __restrict__ B, float* __restrict__ C,
    int M, int N, int K, int lda, int ldb, int ldc,
    long sA, long sB, long sC, int mode)
{
  if (mode == 1 && blockIdx.x > blockIdx.y) return;  // fully-masked score block
  A += (long)blockIdx.z * sA;
  B += (long)blockIdx.z * sB;
  C += (long)blockIdx.z * sC;
  const int tid = threadIdx.x;
  const int m0 = blockIdx.y * 64, n0 = blockIdx.x * 64;
  const int Keff = (mode == 2) ? min(K, m0 + 64) : K;
  __shared__ float As[16][65];
  __shared__ float Bs[16][65];
  const int ty = tid >> 4, tx = tid & 15;
  float acc[4][4] = {};
  for (int k0 = 0; k0 < Keff; k0 += 16) {
    {
      int row = tid >> 2, c4 = (tid & 3) << 2;
      const float4 v = *(const float4*)(A + (long)(m0 + row) * lda + k0 + c4);
      As[c4 + 0][row] = v.x; As[c4 + 1][row] = v.y;
      As[c4 + 2][row] = v.z; As[c4 + 3][row] = v.w;
    }
    if (BT) {
      int row = tid >> 2, c4 = (tid & 3) << 2;
      const float4 v = *(const float4*)(B + (long)(n0 + row) * ldb + k0 + c4);
      Bs[c4 + 0][row] = v.x; Bs[c4 + 1][row] = v.y;
      Bs[c4 + 2][row] = v.z; Bs[c4 + 3][row] = v.w;
    } else {
      int row = tid >> 4, c4 = (tid & 15) << 2;
      const float4 v = *(const float4*)(B + (long)(k0 + row) * ldb + n0 + c4);
      Bs[row][c4 + 0] = v.x; Bs[row][c4 + 1] = v.y;
      Bs[row][c4 + 2] = v.z; Bs[row][c4 + 3] = v.w;
    }
    __syncthreads();
#pragma unroll
    for (int k = 0; k < 16; ++k) {
      float a[4], b[4];
#pragma unroll
      for (int j = 0; j < 4; ++j) a[j] = As[k][ty * 4 + j];
#pragma unroll
      for (int j = 0; j < 4; ++j) b[j] = Bs[k][tx * 4 + j];
#pragma unroll
      for (int i = 0; i < 4; ++i)
#pragma unroll
        for (int j = 0; j < 4; ++j) acc[i][j] = fmaf(a[i], b[j], acc[i][j]);
    }
    __syncthreads();
  }
#pragma unroll
  for (int i = 0; i < 4; ++i)
#pragma unroll
    for (int j = 0; j < 4; ++j)
      C[(long)(m0 + ty * 4 + i) * ldc + n0 + tx * 4 + j] = acc[i][j];
}

// ---------------- RMSNorm (in place, one block per row) ----------------
__global__ __launch_bounds__(256) void rmsnorm_rows(float* x, const float* __restrict__ w, int n) {
  __shared__ float red[4];
  float* row = x + (long)blockIdx.x * n;
  float ss = 0.f;
  for (int i = threadIdx.x; i < n; i += 256) { float v = row[i]; ss += v * v; }
  float tot = block_sum(ss, red);
  float inv = rsqrtf(tot / (float)n + EPS);
  for (int i = threadIdx.x; i < n; i += 256) row[i] = row[i] * inv * w[i];
}

// ---------------- RoPE cos/sin table (double precision, 2048 x 32 each) ----
__global__ void rope_table(float* tab) {
  int s = blockIdx.x, j = threadIdx.x;  // 32 threads
  double freq = pow(10000.0, -(double)j / 32.0);
  double ang = (double)s * freq;
  tab[s * 64 + j] = (float)cos(ang);
  tab[s * 64 + 32 + j] = (float)sin(ang);
}

// ---------------- k_full: rmsnorm(ckv) ++ rope(k_pe) ----------------
__global__ __launch_bounds__(256) void build_kfull(const float* __restrict__ ckv,
                                                   const float* __restrict__ lnw,
                                                   const float* __restrict__ tab,
                                                   float* __restrict__ kf) {
  __shared__ float red[4];
  const int s = blockIdx.x;
  const float* row = ckv + (long)s * 576;
  float ss = 0.f;
  for (int i = threadIdx.x; i < 512; i += 256) { float v = row[i]; ss += v * v; }
  float tot = block_sum(ss, red);
  float inv = rsqrtf(tot / 512.0f + EPS);
  float* out = kf + (long)s * 576;
  for (int i = threadIdx.x; i < 512; i += 256) out[i] = row[i] * inv * lnw[i];
  if (threadIdx.x < 64) {
    int i = threadIdx.x, j = i & 31;
    float c = tab[s * 64 + j], sn = tab[s * 64 + 32 + j];
    float xv = row[512 + i];
    float rot = (i < 32) ? -row[512 + i + 32] : row[512 + i - 32];
    out[512 + i] = xv * c + rot * sn;
  }
}

// ---------------- roped q_pe into q_full[..., 512:576] ----------------
__global__ void rope_qpe(const float* __restrict__ q, const float* __restrict__ tab,
                         float* __restrict__ qf) {
  int s = blockIdx.x, h = blockIdx.y, i = threadIdx.x;  // 64 threads
  int j = i & 31;
  float c = tab[s * 64 + j], sn = tab[s * 64 + 32 + j];
  const float* src = q + (long)s * 3072 + h * 192 + 128;
  float xv = src[i];
  float rot = (i < 32) ? -src[i + 32] : src[i - 32];
  qf[(long)s * 9216 + h * 576 + 512 + i] = xv * c + rot * sn;
}

// ---------------- causal row softmax, in place ----------------
// One block per row s. Applies scale, softmax over k<=s, zeros k>s so the
// downstream PV GEMM can run unmasked.
__global__ __launch_bounds__(256) void softmax_rows(float* __restrict__ sc) {
  __shared__ float red[4];
  const int s = blockIdx.x;
  float* row = sc + (long)s * 2048;
  const int L = s + 1;
  const float scale = 0.07216878364870323f;  // (DN+DR)^-0.5
  float lmax = -INFINITY;
  for (int i = threadIdx.x; i < L; i += 256) lmax = fmaxf(lmax, row[i] * scale);
  float m = block_max(lmax, red);
  float lsum = 0.f;
  for (int i = threadIdx.x; i < L; i += 256) {
    float p = __expf(row[i] * scale - m);
    row[i] = p;  // each thread owns its own indices
    lsum += p;
  }
  float inv = 1.0f / block_sum(lsum, red);
  for (int i = threadIdx.x; i < 2048; i += 256)
    row[i] = (i < L) ? row[i] * inv : 0.f;
}

extern "C" void kernel_launch(void* const* d_in, const int* in_sizes, int n_in,
                              void* d_out, int out_size, void* d_ws, size_t ws_size,
                              hipStream_t stream) {
  const float* x      = (const float*)d_in[0];
  const float* w_q_a  = (const float*)d_in[1];
  const float* q_ln   = (const float*)d_in[2];
  const float* w_q_b  = (const float*)d_in[3];
  const float* w_kv_a = (const float*)d_in[4];
  const float* kv_ln  = (const float*)d_in[5];
  const float* w_kv_b = (const float*)d_in[6];
  const float* w_o    = (const float*)d_in[7];
  float* out = (float*)d_out;
  float* ws  = (float*)d_ws;

  // workspace layout (floats), lifetime-based aliasing:
  float* qa   = ws;                  // 2048*1536 = 3145728   (aliased by ckv)
  float* q    = qa + 3145728;        // 2048*3072 = 6291456   (aliased by o_v)
  float* kf   = q + 6291456;         // 2048*576  = 1179648
  float* qf   = kf + 1179648;        // 2048*16*576 = 18874368
  float* tab  = qf + 18874368;       // 2048*64   = 131072
  float* vall = tab + 131072;        // 16*2048*128 = 4194304
  float* sc   = vall + 4194304;      // 2048*2048 = 4194304 (reused per head)
  float* ckv  = qa;                  // alias: qa dead once q is built
  float* o_v  = q;                   // alias: q dead once q_full is built

  rope_table<<<dim3(2048), dim3(32), 0, stream>>>(tab);

  // q_a = x @ w_q_a ; rmsnorm
  gemm_f32<false><<<dim3(1536 / 64, 2048 / 64), 256, 0, stream>>>(
      x, w_q_a, qa, 2048, 1536, 2048, 2048, 1536, 1536, 0, 0, 0, 0);
  rmsnorm_rows<<<2048, 256, 0, stream>>>(qa, q_ln, 1536);

  // q = q_a @ w_q_b
  gemm_f32<false><<<dim3(3072 / 64, 2048 / 64), 256, 0, stream>>>(
      qa, w_q_b, q, 2048, 3072, 1536, 1536, 3072, 3072, 0, 0, 0, 0);

  // ckv_kpe = x @ w_kv_a (into qa region); k_full = rmsnorm ++ rope
  gemm_f32<false><<<dim3(576 / 64, 2048 / 64), 256, 0, stream>>>(
      x, w_kv_a, ckv, 2048, 576, 2048, 2048, 576, 576, 0, 0, 0, 0);
  build_kfull<<<2048, 256, 0, stream>>>(ckv, kv_ln, tab, kf);

  // q_full[:, h, :512] = q_nope[h] @ w_uk[h]^T   (batched over h)
  gemm_f32<true><<<dim3(512 / 64, 2048 / 64, 16), 256, 0, stream>>>(
      q, w_kv_b, qf, 2048, 512, 128, 3072, 4096, 9216, 192, 256, 576, 0);
  // q_full[:, h, 512:] = rope(q_pe)
  rope_qpe<<<dim3(2048, 16), 64, 0, stream>>>(q, tab, qf);

  // v_all[h] = ckv_norm @ w_uv[h]  (ckv_norm = kf[:, :512]; batched over h)
  gemm_f32<false><<<dim3(128 / 64, 2048 / 64, 16), 256, 0, stream>>>(
      kf, w_kv_b + 128, vall, 2048, 128, 512, 576, 4096, 128, 0, 256, 262144, 0);

  // per-head attention: scores -> softmax -> PV
  for (int h = 0; h < 16; ++h) {
    // scores = q_full[h] @ k_full^T  (causal block-skip)
    gemm_f32<true><<<dim3(2048 / 64, 2048 / 64), 256, 0, stream>>>(
        qf + h * 576, kf, sc, 2048, 2048, 576, 9216, 576, 2048, 0, 0, 0, 1);
    softmax_rows<<<2048, 256, 0, stream>>>(sc);
    // o_v[:, h*128:] = P @ v_all[h]  (causal K-cap)
    gemm_f32<false><<<dim3(128 / 64, 2048 / 64), 256, 0, stream>>>(
        sc, vall + h * 262144, o_v + h * 128, 2048, 128, 2048, 2048, 128, 2048,
        0, 0, 0, 2);
  }

  // y = o_v @ w_o
  gemm_f32<false><<<dim3(2048 / 64, 2048 / 64), 256, 0, stream>>>(
      o_v, w_o, out, 2048, 2048, 2048, 2048, 2048, 2048, 0, 0, 0, 0);
}

// Round 3
// 780.120 us; speedup vs baseline: 18.0273x; 6.8811x over previous
//
#include <hip/hip_runtime.h>
#include <math.h>

// DeepSeek V2 MLA attention — bf16 MFMA GEMMs (m97 structure), fp32 softmax.
// B=1 S=2048 E=2048 H=16 DN=128 DR=64 DV=128 R=512 QLR=1536
// y = softmax(mask(q_full@k_full^T)) @ ckv_n @ w_uv @ w_o  per head.

typedef unsigned short u16;
typedef unsigned int u32;
typedef __bf16 bf16x8 __attribute__((ext_vector_type(8)));
typedef float f32x4 __attribute__((ext_vector_type(4)));

__device__ __forceinline__ u16 f2b(float f) {  // fp32 -> bf16 RNE
  u32 u = __float_as_uint(f);
  u += 0x7FFFu + ((u >> 16) & 1u);
  return (u16)(u >> 16);
}
__device__ __forceinline__ float b2f(u16 v) {
  return __uint_as_float(((u32)v) << 16);
}

#define GLDS(g, l) __builtin_amdgcn_global_load_lds( \
    (const __attribute__((address_space(1))) u32*)(g), \
    (__attribute__((address_space(3))) u32*)(l), 16, 0, 0)

// ---------------- block reduction helpers ----------------
__device__ __forceinline__ float block_sum(float v, float* red) {
#pragma unroll
  for (int off = 32; off > 0; off >>= 1) v += __shfl_down(v, off);
  const int lane = threadIdx.x & 63, w = threadIdx.x >> 6;
  if (lane == 0) red[w] = v;
  __syncthreads();
  float r = red[0] + red[1] + red[2] + red[3];
  __syncthreads();
  return r;
}
__device__ __forceinline__ float block_max(float v, float* red) {
#pragma unroll
  for (int off = 32; off > 0; off >>= 1) v = fmaxf(v, __shfl_down(v, off));
  const int lane = threadIdx.x & 63, w = threadIdx.x >> 6;
  if (lane == 0) red[w] = v;
  __syncthreads();
  float r = fmaxf(fmaxf(red[0], red[1]), fmaxf(red[2], red[3]));
  __syncthreads();
  return r;
}

// ---------------- bf16 MFMA GEMM, 128x128 tile, BK=32 ----------------
// C = A[M,K] @ B[N,K]^T (both row-major bf16). Batched over blockIdx.z.
// OUTK: 0 = fp32 out, 1 = bf16 out, 2 = bf16 transposed out (C[n*ldc+m]).
// MODE: 0 = plain, 1 = causal block-skip (skip bx>by), 2 = causal K-cap.
template<int OUTK, int MODE>
__global__ __launch_bounds__(256) void gemm_mfma(
    const u16* __restrict__ A, const u16* __restrict__ B, void* __restrict__ Cv,
    int K, int lda, int ldb, int ldc, long sA, long sB, long sC)
{
  if (MODE == 1 && blockIdx.x > blockIdx.y) return;
  __shared__ u16 At[4096];  // 128 rows x 32 k, row-major (no pad: global_load_lds)
  __shared__ u16 Bt[4096];
  const u16* Ab = A + (long)blockIdx.z * sA;
  const u16* Bb = B + (long)blockIdx.z * sB;
  const int tid = threadIdx.x;
  const int w = tid >> 6, lane = tid & 63;
  const int m0 = blockIdx.y * 128, n0 = blockIdx.x * 128;
  const int wm = (w >> 1) * 64, wn = (w & 1) * 64;
  const int Keff = (MODE == 2) ? min(K, m0 + 128) : K;
  const int fr = lane & 15, fq = lane >> 4;

  // staging coords: chunk c covers LDS elements [c*512, c*512+512)
  const int c0 = w * 2, c1 = w * 2 + 1;
  const int e0 = (c0 * 64 + lane) * 8, e1 = (c1 * 64 + lane) * 8;
  const int r0 = e0 >> 5, col0 = e0 & 31;
  const int r1 = e1 >> 5, col1 = e1 & 31;

  f32x4 acc[4][4] = {};
  for (int k0 = 0; k0 < Keff; k0 += 32) {
    GLDS(Ab + (long)(m0 + r0) * lda + k0 + col0, At + c0 * 512);
    GLDS(Bb + (long)(n0 + r0) * ldb + k0 + col0, Bt + c0 * 512);
    GLDS(Ab + (long)(m0 + r1) * lda + k0 + col1, At + c1 * 512);
    GLDS(Bb + (long)(n0 + r1) * ldb + k0 + col1, Bt + c1 * 512);
    __syncthreads();
    bf16x8 af[4], bfr[4];
#pragma unroll
    for (int i = 0; i < 4; ++i)
      af[i] = *(const bf16x8*)(At + (wm + i * 16 + fr) * 32 + fq * 8);
#pragma unroll
    for (int j = 0; j < 4; ++j)
      bfr[j] = *(const bf16x8*)(Bt + (wn + j * 16 + fr) * 32 + fq * 8);
#pragma unroll
    for (int i = 0; i < 4; ++i)
#pragma unroll
      for (int j = 0; j < 4; ++j)
        acc[i][j] = __builtin_amdgcn_mfma_f32_16x16x32_bf16(af[i], bfr[j], acc[i][j], 0, 0, 0);
    __syncthreads();
  }

  // epilogue. D mapping (verified m89/m91): col = lane&15, row = (lane>>4)*4 + reg.
  if (OUTK == 0) {
    float* C = (float*)Cv + (long)blockIdx.z * sC;
#pragma unroll
    for (int i = 0; i < 4; ++i)
#pragma unroll
      for (int j = 0; j < 4; ++j) {
        long base = (long)(m0 + wm + i * 16 + fq * 4) * ldc + (n0 + wn + j * 16 + fr);
#pragma unroll
        for (int r = 0; r < 4; ++r) C[base + (long)r * ldc] = acc[i][j][r];
      }
  } else if (OUTK == 1) {
    u16* C = (u16*)Cv + (long)blockIdx.z * sC;
#pragma unroll
    for (int i = 0; i < 4; ++i)
#pragma unroll
      for (int j = 0; j < 4; ++j) {
        long base = (long)(m0 + wm + i * 16 + fq * 4) * ldc + (n0 + wn + j * 16 + fr);
#pragma unroll
        for (int r = 0; r < 4; ++r) C[base + (long)r * ldc] = f2b(acc[i][j][r]);
      }
  } else {
    u16* C = (u16*)Cv + (long)blockIdx.z * sC;
#pragma unroll
    for (int i = 0; i < 4; ++i)
#pragma unroll
      for (int j = 0; j < 4; ++j) {
        ushort4 v = { f2b(acc[i][j][0]), f2b(acc[i][j][1]),
                      f2b(acc[i][j][2]), f2b(acc[i][j][3]) };
        *(ushort4*)(C + (long)(n0 + wn + j * 16 + fr) * ldc + (m0 + wm + i * 16 + fq * 4)) = v;
      }
  }
}

// ---------------- conversion / transpose kernels ----------------
__global__ __launch_bounds__(256) void cast_bf16(const float* __restrict__ in,
                                                 u16* __restrict__ out, long n) {
  long i = ((long)blockIdx.x * 256 + threadIdx.x) * 4;
  if (i >= n) return;
  float4 v = *(const float4*)(in + i);
  ushort4 o = { f2b(v.x), f2b(v.y), f2b(v.z), f2b(v.w) };
  *(ushort4*)(out + i) = o;
}

// out[j*ldo + i] = bf16(in[i*ldi + j]), 32x32 tiles, batched over z.
__global__ __launch_bounds__(256) void transpose_cast(const float* __restrict__ in,
    u16* __restrict__ out, int ldi, int ldo, long sIn, long sOut) {
  in += (long)blockIdx.z * sIn;
  out += (long)blockIdx.z * sOut;
  __shared__ u16 t[32][33];
  const int i0 = blockIdx.y * 32, j0 = blockIdx.x * 32;
  const int tx = threadIdx.x & 31, ty = threadIdx.x >> 5;
  for (int r = ty; r < 32; r += 8)
    t[r][tx] = f2b(in[(long)(i0 + r) * ldi + j0 + tx]);
  __syncthreads();
  for (int r = ty; r < 32; r += 8)
    out[(long)(j0 + r) * ldo + i0 + tx] = t[tx][r];
}

// ---------------- RMSNorm fp32 -> bf16 ----------------
__global__ __launch_bounds__(256) void rmsnorm_cast(const float* __restrict__ in,
    const float* __restrict__ w, u16* __restrict__ out, int n) {
  __shared__ float red[4];
  const float* row = in + (long)blockIdx.x * n;
  u16* orow = out + (long)blockIdx.x * n;
  float ss = 0.f;
  for (int i = threadIdx.x; i < n; i += 256) { float v = row[i]; ss += v * v; }
  float tot = block_sum(ss, red);
  float inv = rsqrtf(tot / (float)n + 1e-6f);
  for (int i = threadIdx.x; i < n; i += 256) orow[i] = f2b(row[i] * inv * w[i]);
}

// ---------------- RoPE table (double precision) ----------------
__global__ void rope_table(float* tab) {
  int s = blockIdx.x, j = threadIdx.x;  // 32 threads
  double freq = pow(10000.0, -(double)j / 32.0);
  double ang = (double)s * freq;
  tab[s * 64 + j] = (float)cos(ang);
  tab[s * 64 + 32 + j] = (float)sin(ang);
}

// ---------------- k_full: rmsnorm(ckv) ++ rope(k_pe) -> bf16 ----------------
__global__ __launch_bounds__(256) void build_kfull(const float* __restrict__ ckv,
    const float* __restrict__ lnw, const float* __restrict__ tab, u16* __restrict__ kfb) {
  __shared__ float red[4];
  const int s = blockIdx.x;
  const float* row = ckv + (long)s * 640;  // padded ld
  float ss = 0.f;
  for (int i = threadIdx.x; i < 512; i += 256) { float v = row[i]; ss += v * v; }
  float tot = block_sum(ss, red);
  float inv = rsqrtf(tot / 512.0f + 1e-6f);
  u16* orow = kfb + (long)s * 576;
  for (int i = threadIdx.x; i < 512; i += 256) orow[i] = f2b(row[i] * inv * lnw[i]);
  if (threadIdx.x < 64) {
    int i = threadIdx.x, j = i & 31;
    float c = tab[s * 64 + j], sn = tab[s * 64 + 32 + j];
    float xv = row[512 + i];
    float rot = (i < 32) ? -row[512 + i + 32] : row[512 + i - 32];
    orow[512 + i] = f2b(xv * c + rot * sn);
  }
}

// ---------------- roped q_pe (bf16 in) into qfb[..., 512:576] ----------------
__global__ void rope_qpe(const u16* __restrict__ qb, const float* __restrict__ tab,
                         u16* __restrict__ qfb) {
  int s = blockIdx.x, h = blockIdx.y, i = threadIdx.x;  // 64 threads
  int j = i & 31;
  float c = tab[s * 64 + j], sn = tab[s * 64 + 32 + j];
  const u16* src = qb + (long)s * 3072 + h * 192 + 128;
  float xv = b2f(src[i]);
  float rot = (i < 32) ? -b2f(src[i + 32]) : b2f(src[i - 32]);
  qfb[(long)s * 9216 + h * 576 + 512 + i] = f2b(xv * c + rot * sn);
}

// ---------------- causal softmax fp32 -> bf16 P (zero-padded to 128) --------
__global__ __launch_bounds__(256) void softmax_bf16(const float* __restrict__ sc,
                                                    u16* __restrict__ Pb) {
  __shared__ float buf[2048];
  __shared__ float red[4];
  const int s = blockIdx.x;
  const float* row = sc + (long)blockIdx.y * 4194304 + (long)s * 2048;
  u16* prow = Pb + (long)blockIdx.y * 4194304 + (long)s * 2048;
  const int L = s + 1, Lpad = ((s >> 7) + 1) << 7;
  const float scale = 0.07216878364870323f;  // 192^-0.5
  float lmax = -1e30f;
  for (int i = threadIdx.x; i < L; i += 256) {
    float v = row[i] * scale; buf[i] = v; lmax = fmaxf(lmax, v);
  }
  float m = block_max(lmax, red);
  float lsum = 0.f;
  for (int i = threadIdx.x; i < L; i += 256) {
    float p = __expf(buf[i] - m); buf[i] = p; lsum += p;
  }
  float inv = 1.0f / block_sum(lsum, red);
  for (int i = threadIdx.x; i < Lpad; i += 256)
    prow[i] = (i < L) ? f2b(buf[i] * inv) : (u16)0;
}

extern "C" void kernel_launch(void* const* d_in, const int* in_sizes, int n_in,
                              void* d_out, int out_size, void* d_ws, size_t ws_size,
                              hipStream_t stream) {
  const float* x      = (const float*)d_in[0];
  const float* w_q_a  = (const float*)d_in[1];
  const float* q_ln   = (const float*)d_in[2];
  const float* w_q_b  = (const float*)d_in[3];
  const float* w_kv_a = (const float*)d_in[4];
  const float* kv_ln  = (const float*)d_in[5];
  const float* w_kv_b = (const float*)d_in[6];
  const float* w_o    = (const float*)d_in[7];
  float* out = (float*)d_out;

  // ---- workspace layout (bytes) ----
  char* p = (char*)d_ws;
  float* tab   = (float*)p;  p += 524288;      // 2048*64 f32
  u16* wkvbb   = (u16*)p;    p += 4194304;     // 512*4096
  u16* wuvT    = (u16*)p;    p += 2097152;     // 16*128*512
  u16* woT     = (u16*)p;    p += 8388608;     // 2048*2048
  u16* qfb     = (u16*)p;    p += 37748736;    // 2048*9216
  u16* vallT   = (u16*)p;    p += 8388608;     // 16*128*2048
  u16* kfb     = (u16*)p;    p += 2359296;     // 2048*576
  u16* ovb     = (u16*)p;    p += 8388608;     // 2048*2048
  char* tb = p;                                // transient region
  // phase 1 (pre-attention):
  u16* xb      = (u16*)tb;                     // 2048*2048
  u16* wqaT    = (u16*)(tb + 8388608);         // 1536*2048
  float* qa    = (float*)(tb + 14680064);      // 2048*1536 f32
  u16* qab     = (u16*)(tb + 27262976);        // 2048*1536
  u16* wqbT    = (u16*)(tb + 33554432);        // 3072*1536
  u16* qb      = (u16*)(tb + 42991616);        // 2048*3072
  u16* wkvaT   = (u16*)(tb + 55574528);        // 640*2048 (pad rows 576.. garbage, unread downstream)
  float* ckv   = (float*)(tb + 58195968);      // 2048*640 f32
  // phase 2 (attention, aliases phase 1):
  long avail = (long)ws_size - (long)(tb - (char*)d_ws);
  int C = 16;
  while (C > 1 && (long)C * 25165824L > avail) C >>= 1;  // sc 16MB + Pb 8MB per head
  float* sc = (float*)tb;
  u16* Pb   = (u16*)(tb + (long)C * 16777216L);

  rope_table<<<dim3(2048), 32, 0, stream>>>(tab);

  // weight prep
  cast_bf16<<<4096, 256, 0, stream>>>(x, xb, 4194304);
  transpose_cast<<<dim3(48, 64), 256, 0, stream>>>(w_q_a, wqaT, 1536, 2048, 0, 0);
  transpose_cast<<<dim3(96, 48), 256, 0, stream>>>(w_q_b, wqbT, 3072, 1536, 0, 0);
  transpose_cast<<<dim3(18, 64), 256, 0, stream>>>(w_kv_a, wkvaT, 576, 2048, 0, 0);
  cast_bf16<<<2048, 256, 0, stream>>>(w_kv_b, wkvbb, 2097152);
  transpose_cast<<<dim3(4, 16, 16), 256, 0, stream>>>(w_kv_b + 128, wuvT, 4096, 512, 256, 65536);
  transpose_cast<<<dim3(64, 64), 256, 0, stream>>>(w_o, woT, 2048, 2048, 0, 0);

  // q_a = x @ w_q_a (f32 out), rmsnorm -> bf16
  gemm_mfma<0, 0><<<dim3(12, 16), 256, 0, stream>>>(
      xb, wqaT, qa, 2048, 2048, 2048, 1536, 0, 0, 0);
  rmsnorm_cast<<<2048, 256, 0, stream>>>(qa, q_ln, qab, 1536);

  // q = q_a @ w_q_b (bf16 out)
  gemm_mfma<1, 0><<<dim3(24, 16), 256, 0, stream>>>(
      qab, wqbT, qb, 1536, 1536, 1536, 3072, 0, 0, 0);

  // ckv_kpe = x @ w_kv_a (f32 out, ld 640); k_full -> bf16
  gemm_mfma<0, 0><<<dim3(5, 16), 256, 0, stream>>>(
      xb, wkvaT, ckv, 2048, 2048, 2048, 640, 0, 0, 0);
  build_kfull<<<2048, 256, 0, stream>>>(ckv, kv_ln, tab, kfb);

  // q_full[:, h, :512] = q_nope[h] @ w_uk[h]^T (bf16 out, batched over h)
  gemm_mfma<1, 0><<<dim3(4, 16, 16), 256, 0, stream>>>(
      qb, wkvbb, qfb, 128, 3072, 4096, 9216, 192, 256, 576);
  rope_qpe<<<dim3(2048, 16), 64, 0, stream>>>(qb, tab, qfb);

  // vallT[h] = (ckv_n @ w_uv[h])^T  (bf16 transposed out)
  gemm_mfma<2, 0><<<dim3(1, 16, 16), 256, 0, stream>>>(
      kfb, wuvT, vallT, 512, 576, 512, 2048, 0, 65536, 262144);

  // attention, C heads per chunk
  for (int h0 = 0; h0 < 16; h0 += C) {
    gemm_mfma<0, 1><<<dim3(16, 16, C), 256, 0, stream>>>(
        qfb + h0 * 576, kfb, sc, 576, 9216, 576, 2048, 576, 0, 4194304);
    softmax_bf16<<<dim3(2048, C), 256, 0, stream>>>(sc, Pb);
    gemm_mfma<1, 2><<<dim3(1, 16, C), 256, 0, stream>>>(
        Pb, vallT + (long)h0 * 262144, ovb + h0 * 128, 2048, 2048, 2048, 2048,
        4194304, 262144, 128);
  }

  // y = o_v @ w_o (f32 out)
  gemm_mfma<0, 0><<<dim3(16, 16), 256, 0, stream>>>(
      ovb, woT, out, 2048, 2048, 2048, 2048, 0, 0, 0);
}

// Round 4
// 597.631 us; speedup vs baseline: 23.5320x; 1.3054x over previous
//
#include <hip/hip_runtime.h>
#include <math.h>

// DeepSeek V2 MLA attention — bf16 MFMA GEMMs + fused flash attention.
// B=1 S=2048 E=2048 H=16 DN=128 DR=64 DV=128 R=512 QLR=1536
// y = softmax(mask(q_full@k_full^T)) @ ckv_n @ w_uv @ w_o  per head.

typedef unsigned short u16;
typedef unsigned int u32;
typedef __bf16 bf16x8 __attribute__((ext_vector_type(8)));
typedef float f32x4 __attribute__((ext_vector_type(4)));

__device__ __forceinline__ u16 f2b(float f) {  // fp32 -> bf16 RNE
  u32 u = __float_as_uint(f);
  u += 0x7FFFu + ((u >> 16) & 1u);
  return (u16)(u >> 16);
}
__device__ __forceinline__ float b2f(u16 v) {
  return __uint_as_float(((u32)v) << 16);
}

#define GLDS(g, l) __builtin_amdgcn_global_load_lds( \
    (const __attribute__((address_space(1))) u32*)(g), \
    (__attribute__((address_space(3))) u32*)(l), 16, 0, 0)

#define MFMA(a, b, c) __builtin_amdgcn_mfma_f32_16x16x32_bf16(a, b, c, 0, 0, 0)

// ---------------- block reduction helper ----------------
__device__ __forceinline__ float block_sum(float v, float* red) {
#pragma unroll
  for (int off = 32; off > 0; off >>= 1) v += __shfl_down(v, off);
  const int lane = threadIdx.x & 63, w = threadIdx.x >> 6;
  if (lane == 0) red[w] = v;
  __syncthreads();
  float r = red[0] + red[1] + red[2] + red[3];
  __syncthreads();
  return r;
}

// ---------------- bf16 MFMA GEMM, 128x128 tile, BK=32 (m97 structure) -------
// C = A[M,K] @ B[N,K]^T (both row-major bf16). Batched over blockIdx.z.
// OUTK: 0 = fp32 out, 1 = bf16 out, 2 = bf16 transposed out (C[n*ldc+m]).
template<int OUTK>
__global__ __launch_bounds__(256) void gemm_mfma(
    const u16* __restrict__ A, const u16* __restrict__ B, void* __restrict__ Cv,
    int K, int lda, int ldb, int ldc, long sA, long sB, long sC)
{
  __shared__ u16 At[4096];  // 128 rows x 32 k (no pad: global_load_lds)
  __shared__ u16 Bt[4096];
  const u16* Ab = A + (long)blockIdx.z * sA;
  const u16* Bb = B + (long)blockIdx.z * sB;
  const int tid = threadIdx.x;
  const int w = tid >> 6, lane = tid & 63;
  const int m0 = blockIdx.y * 128, n0 = blockIdx.x * 128;
  const int wm = (w >> 1) * 64, wn = (w & 1) * 64;
  const int fr = lane & 15, fq = lane >> 4;

  const int c0 = w * 2, c1 = w * 2 + 1;
  const int e0 = (c0 * 64 + lane) * 8, e1 = (c1 * 64 + lane) * 8;
  const int r0 = e0 >> 5, col0 = e0 & 31;
  const int r1 = e1 >> 5, col1 = e1 & 31;

  f32x4 acc[4][4] = {};
  for (int k0 = 0; k0 < K; k0 += 32) {
    GLDS(Ab + (long)(m0 + r0) * lda + k0 + col0, At + c0 * 512);
    GLDS(Bb + (long)(n0 + r0) * ldb + k0 + col0, Bt + c0 * 512);
    GLDS(Ab + (long)(m0 + r1) * lda + k0 + col1, At + c1 * 512);
    GLDS(Bb + (long)(n0 + r1) * ldb + k0 + col1, Bt + c1 * 512);
    __syncthreads();
    bf16x8 af[4], bfr[4];
#pragma unroll
    for (int i = 0; i < 4; ++i)
      af[i] = *(const bf16x8*)(At + (wm + i * 16 + fr) * 32 + fq * 8);
#pragma unroll
    for (int j = 0; j < 4; ++j)
      bfr[j] = *(const bf16x8*)(Bt + (wn + j * 16 + fr) * 32 + fq * 8);
#pragma unroll
    for (int i = 0; i < 4; ++i)
#pragma unroll
      for (int j = 0; j < 4; ++j)
        acc[i][j] = MFMA(af[i], bfr[j], acc[i][j]);
    __syncthreads();
  }

  // D mapping (verified m89/m91): col = lane&15, row = (lane>>4)*4 + reg.
  if (OUTK == 0) {
    float* C = (float*)Cv + (long)blockIdx.z * sC;
#pragma unroll
    for (int i = 0; i < 4; ++i)
#pragma unroll
      for (int j = 0; j < 4; ++j) {
        long base = (long)(m0 + wm + i * 16 + fq * 4) * ldc + (n0 + wn + j * 16 + fr);
#pragma unroll
        for (int r = 0; r < 4; ++r) C[base + (long)r * ldc] = acc[i][j][r];
      }
  } else if (OUTK == 1) {
    u16* C = (u16*)Cv + (long)blockIdx.z * sC;
#pragma unroll
    for (int i = 0; i < 4; ++i)
#pragma unroll
      for (int j = 0; j < 4; ++j) {
        long base = (long)(m0 + wm + i * 16 + fq * 4) * ldc + (n0 + wn + j * 16 + fr);
#pragma unroll
        for (int r = 0; r < 4; ++r) C[base + (long)r * ldc] = f2b(acc[i][j][r]);
      }
  } else {
    u16* C = (u16*)Cv + (long)blockIdx.z * sC;
#pragma unroll
    for (int i = 0; i < 4; ++i)
#pragma unroll
      for (int j = 0; j < 4; ++j) {
        ushort4 v = { f2b(acc[i][j][0]), f2b(acc[i][j][1]),
                      f2b(acc[i][j][2]), f2b(acc[i][j][3]) };
        *(ushort4*)(C + (long)(n0 + wn + j * 16 + fr) * ldc + (m0 + wm + i * 16 + fq * 4)) = v;
      }
  }
}

// ---------------- fused flash attention ----------------
// grid: (16 heads, 32 q-tiles of 64 rows), 256 threads.
// Per block: rows [q0, q0+64) of head h. Loops K-tiles of 128, online softmax.
// QK wave layout: 2x2 (qw = w>>1 owns 32 rows, kw = w&1 owns 64 k-cols).
// PV wave layout: same rows, kw doubles as v-col half.
__global__ __launch_bounds__(256, 2) void attn_flash(
    const u16* __restrict__ qfb,   // [2048][16*576]
    const u16* __restrict__ kfb,   // [2048][576]
    const u16* __restrict__ vallT, // [16][128][2048]  (v-col major)
    u16* __restrict__ ovb)         // [2048][2048]
{
  __shared__ u16 Qs[64 * 32];          // 4 KB
  __shared__ u16 Ks[128 * 32];         // 8 KB
  __shared__ u16 Ps[64 * 136];         // 17.4 KB (pad 136: 2-way conflicts only)
  __shared__ u16 Vs[128 * 136];        // 34.8 KB
  __shared__ float stats[2][64][2];    // [kw][row][{m,s}] 1 KB

  const int h = blockIdx.x;
  const int qt = 31 - blockIdx.y;      // heavy q-tiles dispatch first
  const int q0 = qt * 64;
  const int tid = threadIdx.x;
  const int w = tid >> 6, lane = tid & 63;
  const int fr = lane & 15, fq = lane >> 4;
  const int qw = w >> 1, kw = w & 1;
  const float scale = 0.07216878364870323f;  // (DN+DR)^-0.5
  const int ktiles = (qt >> 1) + 1;

  float m_prev[2][4], l_run[2][4];
#pragma unroll
  for (int i = 0; i < 2; ++i)
#pragma unroll
    for (int r = 0; r < 4; ++r) { m_prev[i][r] = -1e30f; l_run[i][r] = 0.f; }
  f32x4 Oacc[2][4] = {};

  // staging coords (Q: chunk w of 4; K: chunks 2w, 2w+1 of 8)
  const int qe = w * 512 + lane * 8;
  const int qrow = qe >> 5, qcol = qe & 31;
  const int ke0 = (2 * w) * 512 + lane * 8, ke1 = (2 * w + 1) * 512 + lane * 8;
  const int krow0 = ke0 >> 5, kcol0 = ke0 & 31;
  const int krow1 = ke1 >> 5, kcol1 = ke1 & 31;
  const u16* qbase = qfb + (long)q0 * 9216 + h * 576;

  for (int kt = 0; kt < ktiles; ++kt) {
    const int k0 = kt * 128;

    // ---- scores: QK^T over d=576 in BK=32 steps ----
    f32x4 sc[2][4] = {};
    for (int d0 = 0; d0 < 576; d0 += 32) {
      GLDS(qbase + (long)qrow * 9216 + d0 + qcol, Qs + w * 512);
      GLDS(kfb + (long)(k0 + krow0) * 576 + d0 + kcol0, Ks + 2 * w * 512);
      GLDS(kfb + (long)(k0 + krow1) * 576 + d0 + kcol1, Ks + (2 * w + 1) * 512);
      __syncthreads();
      bf16x8 a0 = *(const bf16x8*)(Qs + (qw * 32 + fr) * 32 + fq * 8);
      bf16x8 a1 = *(const bf16x8*)(Qs + (qw * 32 + 16 + fr) * 32 + fq * 8);
#pragma unroll
      for (int j = 0; j < 4; ++j) {
        bf16x8 b = *(const bf16x8*)(Ks + (kw * 64 + j * 16 + fr) * 32 + fq * 8);
        sc[0][j] = MFMA(a0, b, sc[0][j]);
        sc[1][j] = MFMA(a1, b, sc[1][j]);
      }
      __syncthreads();
    }

    // ---- V tile global loads (consumed by ds_write after stats) ----
    uint4 vreg[8];
    const u16* vbase = vallT + (long)h * 262144 + k0;
#pragma unroll
    for (int v = 0; v < 8; ++v) {
      int c = v * 256 + tid, row = c >> 4, cc = c & 15;
      vreg[v] = *(const uint4*)(vbase + (long)row * 2048 + cc * 8);
    }

    // ---- per-wave partial softmax (scale, mask, local max/sum) ----
    const bool diag = (kt == (qt >> 1));
    float pm[2][4], ps[2][4];
#pragma unroll
    for (int i = 0; i < 2; ++i) {
#pragma unroll
      for (int r = 0; r < 4; ++r) {
        float mx = -1e30f;
#pragma unroll
        for (int j = 0; j < 4; ++j) {
          float s = sc[i][j][r] * scale;
          if (diag) {
            int row = q0 + qw * 32 + i * 16 + fq * 4 + r;
            int col = k0 + kw * 64 + j * 16 + fr;
            if (col > row) s = -1e30f;
          }
          sc[i][j][r] = s;
          mx = fmaxf(mx, s);
        }
        mx = fmaxf(mx, __shfl_xor(mx, 1));
        mx = fmaxf(mx, __shfl_xor(mx, 2));
        mx = fmaxf(mx, __shfl_xor(mx, 4));
        mx = fmaxf(mx, __shfl_xor(mx, 8));
        pm[i][r] = mx;
        float sum = 0.f;
#pragma unroll
        for (int j = 0; j < 4; ++j) {
          float p = __expf(sc[i][j][r] - mx);  // if mx==-1e30 (all-masked half),
          sc[i][j][r] = p;                     // killed below by exp(pm-mn)==0
          sum += p;
        }
        sum += __shfl_xor(sum, 1);
        sum += __shfl_xor(sum, 2);
        sum += __shfl_xor(sum, 4);
        sum += __shfl_xor(sum, 8);
        ps[i][r] = sum;
      }
    }
    if (fr == 0) {
#pragma unroll
      for (int i = 0; i < 2; ++i)
#pragma unroll
        for (int r = 0; r < 4; ++r) {
          int lr = qw * 32 + i * 16 + fq * 4 + r;
          stats[kw][lr][0] = pm[i][r];
          stats[kw][lr][1] = ps[i][r];
        }
    }
    __syncthreads();

    // ---- combine halves, online update, write P, rescale O ----
#pragma unroll
    for (int i = 0; i < 2; ++i)
#pragma unroll
      for (int r = 0; r < 4; ++r) {
        int lr = qw * 32 + i * 16 + fq * 4 + r;
        float mA = stats[0][lr][0], sA = stats[0][lr][1];
        float mB = stats[1][lr][0], sB = stats[1][lr][1];
        float mt = fmaxf(mA, mB);
        float lt = sA * __expf(mA - mt) + sB * __expf(mB - mt);
        float mn = fmaxf(m_prev[i][r], mt);
        float alpha = __expf(m_prev[i][r] - mn);
        l_run[i][r] = l_run[i][r] * alpha + lt * __expf(mt - mn);
        float rs = __expf(pm[i][r] - mn);
        m_prev[i][r] = mn;
#pragma unroll
        for (int j = 0; j < 4; ++j)
          Ps[lr * 136 + kw * 64 + j * 16 + fr] = f2b(sc[i][j][r] * rs);
#pragma unroll
        for (int jv = 0; jv < 4; ++jv)
          Oacc[i][jv][r] *= alpha;
      }

    // ---- stage V (padded) ----
#pragma unroll
    for (int v = 0; v < 8; ++v) {
      int c = v * 256 + tid, row = c >> 4, cc = c & 15;
      *(uint4*)(Vs + row * 136 + cc * 8) = vreg[v];
    }
    __syncthreads();

    // ---- PV: O += P @ V^T ----
#pragma unroll
    for (int ks = 0; ks < 4; ++ks) {
      bf16x8 pa0 = *(const bf16x8*)(Ps + (qw * 32 + fr) * 136 + ks * 32 + fq * 8);
      bf16x8 pa1 = *(const bf16x8*)(Ps + (qw * 32 + 16 + fr) * 136 + ks * 32 + fq * 8);
#pragma unroll
      for (int jv = 0; jv < 4; ++jv) {
        bf16x8 vb = *(const bf16x8*)(Vs + (kw * 64 + jv * 16 + fr) * 136 + ks * 32 + fq * 8);
        Oacc[0][jv] = MFMA(pa0, vb, Oacc[0][jv]);
        Oacc[1][jv] = MFMA(pa1, vb, Oacc[1][jv]);
      }
    }
    __syncthreads();  // protect Ps/Vs before next tile overwrites
  }

  // ---- normalize + write ----
#pragma unroll
  for (int i = 0; i < 2; ++i)
#pragma unroll
    for (int r = 0; r < 4; ++r) {
      float inv = 1.0f / l_run[i][r];
      int row = q0 + qw * 32 + i * 16 + fq * 4 + r;
#pragma unroll
      for (int jv = 0; jv < 4; ++jv) {
        int col = h * 128 + kw * 64 + jv * 16 + fr;
        ovb[(long)row * 2048 + col] = f2b(Oacc[i][jv][r] * inv);
      }
    }
}

// ---------------- conversion / transpose kernels ----------------
__global__ __launch_bounds__(256) void cast_bf16(const float* __restrict__ in,
                                                 u16* __restrict__ out, long n) {
  long i = ((long)blockIdx.x * 256 + threadIdx.x) * 4;
  if (i >= n) return;
  float4 v = *(const float4*)(in + i);
  ushort4 o = { f2b(v.x), f2b(v.y), f2b(v.z), f2b(v.w) };
  *(ushort4*)(out + i) = o;
}

__global__ __launch_bounds__(256) void transpose_cast(const float* __restrict__ in,
    u16* __restrict__ out, int ldi, int ldo, long sIn, long sOut) {
  in += (long)blockIdx.z * sIn;
  out += (long)blockIdx.z * sOut;
  __shared__ u16 t[32][33];
  const int i0 = blockIdx.y * 32, j0 = blockIdx.x * 32;
  const int tx = threadIdx.x & 31, ty = threadIdx.x >> 5;
  for (int r = ty; r < 32; r += 8)
    t[r][tx] = f2b(in[(long)(i0 + r) * ldi + j0 + tx]);
  __syncthreads();
  for (int r = ty; r < 32; r += 8)
    out[(long)(j0 + r) * ldo + i0 + tx] = t[tx][r];
}

// ---------------- RMSNorm fp32 -> bf16 ----------------
__global__ __launch_bounds__(256) void rmsnorm_cast(const float* __restrict__ in,
    const float* __restrict__ w, u16* __restrict__ out, int n) {
  __shared__ float red[4];
  const float* row = in + (long)blockIdx.x * n;
  u16* orow = out + (long)blockIdx.x * n;
  float ss = 0.f;
  for (int i = threadIdx.x; i < n; i += 256) { float v = row[i]; ss += v * v; }
  float tot = block_sum(ss, red);
  float inv = rsqrtf(tot / (float)n + 1e-6f);
  for (int i = threadIdx.x; i < n; i += 256) orow[i] = f2b(row[i] * inv * w[i]);
}

// ---------------- RoPE table (double precision) ----------------
__global__ void rope_table(float* tab) {
  int s = blockIdx.x, j = threadIdx.x;  // 32 threads
  double freq = pow(10000.0, -(double)j / 32.0);
  double ang = (double)s * freq;
  tab[s * 64 + j] = (float)cos(ang);
  tab[s * 64 + 32 + j] = (float)sin(ang);
}

// ---------------- k_full: rmsnorm(ckv) ++ rope(k_pe) -> bf16 ----------------
__global__ __launch_bounds__(256) void build_kfull(const float* __restrict__ ckv,
    const float* __restrict__ lnw, const float* __restrict__ tab, u16* __restrict__ kfb) {
  __shared__ float red[4];
  const int s = blockIdx.x;
  const float* row = ckv + (long)s * 640;  // padded ld
  float ss = 0.f;
  for (int i = threadIdx.x; i < 512; i += 256) { float v = row[i]; ss += v * v; }
  float tot = block_sum(ss, red);
  float inv = rsqrtf(tot / 512.0f + 1e-6f);
  u16* orow = kfb + (long)s * 576;
  for (int i = threadIdx.x; i < 512; i += 256) orow[i] = f2b(row[i] * inv * lnw[i]);
  if (threadIdx.x < 64) {
    int i = threadIdx.x, j = i & 31;
    float c = tab[s * 64 + j], sn = tab[s * 64 + 32 + j];
    float xv = row[512 + i];
    float rot = (i < 32) ? -row[512 + i + 32] : row[512 + i - 32];
    orow[512 + i] = f2b(xv * c + rot * sn);
  }
}

// ---------------- roped q_pe (bf16 in) into qfb[..., 512:576] ----------------
__global__ void rope_qpe(const u16* __restrict__ qb, const float* __restrict__ tab,
                         u16* __restrict__ qfb) {
  int s = blockIdx.x, h = blockIdx.y, i = threadIdx.x;  // 64 threads
  int j = i & 31;
  float c = tab[s * 64 + j], sn = tab[s * 64 + 32 + j];
  const u16* src = qb + (long)s * 3072 + h * 192 + 128;
  float xv = b2f(src[i]);
  float rot = (i < 32) ? -b2f(src[i + 32]) : b2f(src[i - 32]);
  qfb[(long)s * 9216 + h * 576 + 512 + i] = f2b(xv * c + rot * sn);
}

extern "C" void kernel_launch(void* const* d_in, const int* in_sizes, int n_in,
                              void* d_out, int out_size, void* d_ws, size_t ws_size,
                              hipStream_t stream) {
  const float* x      = (const float*)d_in[0];
  const float* w_q_a  = (const float*)d_in[1];
  const float* q_ln   = (const float*)d_in[2];
  const float* w_q_b  = (const float*)d_in[3];
  const float* w_kv_a = (const float*)d_in[4];
  const float* kv_ln  = (const float*)d_in[5];
  const float* w_kv_b = (const float*)d_in[6];
  const float* w_o    = (const float*)d_in[7];
  float* out = (float*)d_out;

  // ---- workspace layout (bytes) ----
  char* p = (char*)d_ws;
  float* tab   = (float*)p;  p += 524288;      // 2048*64 f32
  u16* wkvbb   = (u16*)p;    p += 4194304;     // 512*4096
  u16* wuvT    = (u16*)p;    p += 2097152;     // 16*128*512
  u16* woT     = (u16*)p;    p += 8388608;     // 2048*2048
  u16* qfb     = (u16*)p;    p += 37748736;    // 2048*9216
  u16* vallT   = (u16*)p;    p += 8388608;     // 16*128*2048
  u16* kfb     = (u16*)p;    p += 2359296;     // 2048*576
  u16* ovb     = (u16*)p;    p += 8388608;     // 2048*2048
  char* tb = p;                                // transient (phase-1 only)
  u16* xb      = (u16*)tb;                     // 2048*2048
  u16* wqaT    = (u16*)(tb + 8388608);         // 1536*2048
  float* qa    = (float*)(tb + 14680064);      // 2048*1536 f32
  u16* qab     = (u16*)(tb + 27262976);        // 2048*1536
  u16* wqbT    = (u16*)(tb + 33554432);        // 3072*1536
  u16* qb      = (u16*)(tb + 42991616);        // 2048*3072
  u16* wkvaT   = (u16*)(tb + 55574528);        // 640*2048 (pad rows unread)
  float* ckv   = (float*)(tb + 58195968);      // 2048*640 f32

  rope_table<<<dim3(2048), 32, 0, stream>>>(tab);

  // weight prep
  cast_bf16<<<4096, 256, 0, stream>>>(x, xb, 4194304);
  transpose_cast<<<dim3(48, 64), 256, 0, stream>>>(w_q_a, wqaT, 1536, 2048, 0, 0);
  transpose_cast<<<dim3(96, 48), 256, 0, stream>>>(w_q_b, wqbT, 3072, 1536, 0, 0);
  transpose_cast<<<dim3(18, 64), 256, 0, stream>>>(w_kv_a, wkvaT, 576, 2048, 0, 0);
  cast_bf16<<<2048, 256, 0, stream>>>(w_kv_b, wkvbb, 2097152);
  transpose_cast<<<dim3(4, 16, 16), 256, 0, stream>>>(w_kv_b + 128, wuvT, 4096, 512, 256, 65536);
  transpose_cast<<<dim3(64, 64), 256, 0, stream>>>(w_o, woT, 2048, 2048, 0, 0);

  // q_a = x @ w_q_a (f32 out), rmsnorm -> bf16
  gemm_mfma<0><<<dim3(12, 16), 256, 0, stream>>>(
      xb, wqaT, qa, 2048, 2048, 2048, 1536, 0, 0, 0);
  rmsnorm_cast<<<2048, 256, 0, stream>>>(qa, q_ln, qab, 1536);

  // q = q_a @ w_q_b (bf16 out)
  gemm_mfma<1><<<dim3(24, 16), 256, 0, stream>>>(
      qab, wqbT, qb, 1536, 1536, 1536, 3072, 0, 0, 0);

  // ckv_kpe = x @ w_kv_a (f32 out, ld 640); k_full -> bf16
  gemm_mfma<0><<<dim3(5, 16), 256, 0, stream>>>(
      xb, wkvaT, ckv, 2048, 2048, 2048, 640, 0, 0, 0);
  build_kfull<<<2048, 256, 0, stream>>>(ckv, kv_ln, tab, kfb);

  // q_full[:, h, :512] = q_nope[h] @ w_uk[h]^T (bf16 out, batched over h)
  gemm_mfma<1><<<dim3(4, 16, 16), 256, 0, stream>>>(
      qb, wkvbb, qfb, 128, 3072, 4096, 9216, 192, 256, 576);
  rope_qpe<<<dim3(2048, 16), 64, 0, stream>>>(qb, tab, qfb);

  // vallT[h] = (ckv_n @ w_uv[h])^T  (bf16 transposed out)
  gemm_mfma<2><<<dim3(1, 16, 16), 256, 0, stream>>>(
      kfb, wuvT, vallT, 512, 576, 512, 2048, 0, 65536, 262144);

  // fused flash attention -> ovb
  attn_flash<<<dim3(16, 32), 256, 0, stream>>>(qfb, kfb, vallT, ovb);

  // y = o_v @ w_o (f32 out)
  gemm_mfma<0><<<dim3(16, 16), 256, 0, stream>>>(
      ovb, woT, out, 2048, 2048, 2048, 2048, 0, 0, 0);
}

// Round 6
// 577.043 us; speedup vs baseline: 24.3716x; 1.0357x over previous
//
#include <hip/hip_runtime.h>
#include <math.h>

// DeepSeek V2 MLA attention — bf16 MFMA GEMMs + fused flash attention v2.
// B=1 S=2048 E=2048 H=16 DN=128 DR=64 DV=128 R=512 QLR=1536
// y = softmax(mask(q_full@k_full^T)) @ ckv_n @ w_uv @ w_o  per head.

typedef unsigned short u16;
typedef unsigned int u32;
typedef __bf16 bf16x8 __attribute__((ext_vector_type(8)));
typedef float f32x4 __attribute__((ext_vector_type(4)));

__device__ __forceinline__ u16 f2b(float f) {  // fp32 -> bf16 RNE
  u32 u = __float_as_uint(f);
  u += 0x7FFFu + ((u >> 16) & 1u);
  return (u16)(u >> 16);
}
__device__ __forceinline__ float b2f(u16 v) {
  return __uint_as_float(((u32)v) << 16);
}

#define GLDS(g, l) __builtin_amdgcn_global_load_lds( \
    (const __attribute__((address_space(1))) u32*)(g), \
    (__attribute__((address_space(3))) u32*)(l), 16, 0, 0)

#define MFMA(a, b, c) __builtin_amdgcn_mfma_f32_16x16x32_bf16(a, b, c, 0, 0, 0)

// ---------------- block reduction helper ----------------
__device__ __forceinline__ float block_sum(float v, float* red) {
#pragma unroll
  for (int off = 32; off > 0; off >>= 1) v += __shfl_down(v, off);
  const int lane = threadIdx.x & 63, w = threadIdx.x >> 6;
  if (lane == 0) red[w] = v;
  __syncthreads();
  float r = red[0] + red[1] + red[2] + red[3];
  __syncthreads();
  return r;
}

// ---------------- bf16 MFMA GEMM, 128x128 tile, BK=32 (m97 structure) -------
// C = A[M,K] @ B[N,K]^T (both row-major bf16). Batched over blockIdx.z.
// OUTK: 0 = fp32 out, 1 = bf16 out, 2 = bf16 transposed out (C[n*ldc+m]).
template<int OUTK>
__global__ __launch_bounds__(256) void gemm_mfma(
    const u16* __restrict__ A, const u16* __restrict__ B, void* __restrict__ Cv,
    int K, int lda, int ldb, int ldc, long sA, long sB, long sC)
{
  __shared__ u16 At[4096];  // 128 rows x 32 k (no pad: global_load_lds)
  __shared__ u16 Bt[4096];
  const u16* Ab = A + (long)blockIdx.z * sA;
  const u16* Bb = B + (long)blockIdx.z * sB;
  const int tid = threadIdx.x;
  const int w = tid >> 6, lane = tid & 63;
  const int m0 = blockIdx.y * 128, n0 = blockIdx.x * 128;
  const int wm = (w >> 1) * 64, wn = (w & 1) * 64;
  const int fr = lane & 15, fq = lane >> 4;

  const int c0 = w * 2, c1 = w * 2 + 1;
  const int e0 = (c0 * 64 + lane) * 8, e1 = (c1 * 64 + lane) * 8;
  const int r0 = e0 >> 5, col0 = e0 & 31;
  const int r1 = e1 >> 5, col1 = e1 & 31;

  f32x4 acc[4][4] = {};
  for (int k0 = 0; k0 < K; k0 += 32) {
    GLDS(Ab + (long)(m0 + r0) * lda + k0 + col0, At + c0 * 512);
    GLDS(Bb + (long)(n0 + r0) * ldb + k0 + col0, Bt + c0 * 512);
    GLDS(Ab + (long)(m0 + r1) * lda + k0 + col1, At + c1 * 512);
    GLDS(Bb + (long)(n0 + r1) * ldb + k0 + col1, Bt + c1 * 512);
    __syncthreads();
    bf16x8 af[4], bfr[4];
#pragma unroll
    for (int i = 0; i < 4; ++i)
      af[i] = *(const bf16x8*)(At + (wm + i * 16 + fr) * 32 + fq * 8);
#pragma unroll
    for (int j = 0; j < 4; ++j)
      bfr[j] = *(const bf16x8*)(Bt + (wn + j * 16 + fr) * 32 + fq * 8);
#pragma unroll
    for (int i = 0; i < 4; ++i)
#pragma unroll
      for (int j = 0; j < 4; ++j)
        acc[i][j] = MFMA(af[i], bfr[j], acc[i][j]);
    __syncthreads();
  }

  // D mapping (verified m89/m91): col = lane&15, row = (lane>>4)*4 + reg.
  if (OUTK == 0) {
    float* C = (float*)Cv + (long)blockIdx.z * sC;
#pragma unroll
    for (int i = 0; i < 4; ++i)
#pragma unroll
      for (int j = 0; j < 4; ++j) {
        long base = (long)(m0 + wm + i * 16 + fq * 4) * ldc + (n0 + wn + j * 16 + fr);
#pragma unroll
        for (int r = 0; r < 4; ++r) C[base + (long)r * ldc] = acc[i][j][r];
      }
  } else if (OUTK == 1) {
    u16* C = (u16*)Cv + (long)blockIdx.z * sC;
#pragma unroll
    for (int i = 0; i < 4; ++i)
#pragma unroll
      for (int j = 0; j < 4; ++j) {
        long base = (long)(m0 + wm + i * 16 + fq * 4) * ldc + (n0 + wn + j * 16 + fr);
#pragma unroll
        for (int r = 0; r < 4; ++r) C[base + (long)r * ldc] = f2b(acc[i][j][r]);
      }
  } else {
    u16* C = (u16*)Cv + (long)blockIdx.z * sC;
#pragma unroll
    for (int i = 0; i < 4; ++i)
#pragma unroll
      for (int j = 0; j < 4; ++j) {
        ushort4 v = { f2b(acc[i][j][0]), f2b(acc[i][j][1]),
                      f2b(acc[i][j][2]), f2b(acc[i][j][3]) };
        *(ushort4*)(C + (long)(n0 + wn + j * 16 + fr) * ldc + (m0 + wm + i * 16 + fq * 4)) = v;
      }
  }
}

// ---------------- fused flash attention v2 ----------------
// grid (16 heads, 32 q-tiles of 64 rows), 256 threads.
// Wave w owns q-rows [q0+16w, q0+16w+16) x all 128 k-cols of each K-tile:
//   - Q A-frags resident in registers (loaded once, 72 VGPRs)
//   - wave-local online softmax (no cross-wave stats)
//   - K double-buffered via global_load_lds (XOR-swizzled, 4-way max)
//   - V staged via global_load_lds (XOR-swizzled, 2-way = free)
__global__ __launch_bounds__(256, 2) void attn_flash2(
    const u16* __restrict__ qfb,   // [2048][16*576]
    const u16* __restrict__ kfb,   // [2048][576]
    const u16* __restrict__ vallT, // [16][128][2048]  (v-col major)
    u16* __restrict__ ovb)         // [2048][2048]
{
  __shared__ u16 Ks[2 * 4096];   // 16 KB: K chunk dbuf, [row 128][g'=g^(row&3)][8]
  __shared__ u16 Vs[16384];      // 32 KB: [vcol 128][s: holds g=s^(vcol&15)][8]
  __shared__ u16 Ps[4 * 2176];   // 17 KB: per-wave P, 16 rows x 136 stride

  const int h = blockIdx.x;
  const int y = blockIdx.y;
  const int qt = (y & 1) ? (y >> 1) : (31 - (y >> 1));  // pair heavy+light
  const int q0 = qt * 64;
  const int tid = threadIdx.x;
  const int w = tid >> 6, lane = tid & 63;
  const int fr = lane & 15, fq = lane >> 4;
  const float scale = 0.07216878364870323f;  // (DN+DR)^-0.5
  const int ktiles = (qt >> 1) + 1;
  u16* Psw = Ps + w * 2176;

  // ---- Q fragments, resident (A[m=lane&15=fr][k=fq*8+j]) ----
  bf16x8 aq[18];
  {
    const u16* qp = qfb + (long)(q0 + w * 16 + fr) * 9216 + h * 576 + fq * 8;
#pragma unroll
    for (int d = 0; d < 18; ++d) aq[d] = *(const bf16x8*)(qp + d * 32);
  }

  // K staging coords: instr i=w*2+c covers LDS bytes [i*1024, i*1024+1024)
  const int krow0 = (w * 2) * 16 + (lane >> 2);
  const int krow1 = (w * 2 + 1) * 16 + (lane >> 2);
  const int kg0 = (lane & 3) ^ (krow0 & 3);
  const int kg1 = (lane & 3) ^ (krow1 & 3);
  // V staging coords: instr i=w*8+c covers vcols [i*4, i*4+4); 32 instrs total
  const int vlanecol = lane >> 4;             // 0..3 within 4-vcol group
  const int vslot = lane & 15;

  float m_run[4], l_run[4];
#pragma unroll
  for (int r = 0; r < 4; ++r) { m_run[r] = -1e30f; l_run[r] = 0.f; }
  f32x4 Oacc[8] = {};
  const u16* vbase = vallT + (long)h * 262144;

  for (int kt = 0; kt < ktiles; ++kt) {
    const int k0 = kt * 128;

    // ---- prime K chunk 0 into buf 0 ----
    GLDS(kfb + (long)(k0 + krow0) * 576 + kg0 * 8, Ks + (w * 2) * 512);
    GLDS(kfb + (long)(k0 + krow1) * 576 + kg1 * 8, Ks + (w * 2 + 1) * 512);
    __syncthreads();

    // ---- QK^T: 18 double-buffered BK=32 steps ----
    f32x4 sc[8] = {};
#pragma unroll
    for (int d = 0; d < 18; ++d) {
      if (d < 17) {  // issue next chunk before compute (overlaps)
        const int d0 = (d + 1) * 32;
        u16* dst = Ks + ((d + 1) & 1) * 4096;
        GLDS(kfb + (long)(k0 + krow0) * 576 + d0 + kg0 * 8, dst + (w * 2) * 512);
        GLDS(kfb + (long)(k0 + krow1) * 576 + d0 + kg1 * 8, dst + (w * 2 + 1) * 512);
      }
      const u16* kb = Ks + (d & 1) * 4096;
#pragma unroll
      for (int j = 0; j < 8; ++j) {
        const int row = j * 16 + fr;
        bf16x8 b = *(const bf16x8*)(kb + row * 32 + ((fq ^ (row & 3)) * 8));
        sc[j] = MFMA(aq[d], b, sc[j]);
      }
      __syncthreads();  // drains just-issued GLDS + protects buffer reuse
    }

    // ---- issue V stage: 8 GLDS/wave, 32 total -> all 128 vcols ----
#pragma unroll
    for (int c = 0; c < 8; ++c) {
      const int i = w * 8 + c;
      const int vcol = i * 4 + vlanecol;
      const int g = vslot ^ (vcol & 15);
      GLDS(vbase + (long)vcol * 2048 + k0 + g * 8, Vs + i * 512);
    }

    // ---- wave-local online softmax ----
    const bool diag = (kt == ktiles - 1);
#pragma unroll
    for (int r = 0; r < 4; ++r) {
      float mx = m_run[r];
#pragma unroll
      for (int j = 0; j < 8; ++j) {
        float s = sc[j][r] * scale;
        if (diag) {
          const int row = q0 + w * 16 + fq * 4 + r;
          const int col = k0 + j * 16 + fr;
          if (col > row) s = -1e30f;
        }
        sc[j][r] = s;
        mx = fmaxf(mx, s);
      }
      mx = fmaxf(mx, __shfl_xor(mx, 1));
      mx = fmaxf(mx, __shfl_xor(mx, 2));
      mx = fmaxf(mx, __shfl_xor(mx, 4));
      mx = fmaxf(mx, __shfl_xor(mx, 8));
      const float alpha = __expf(m_run[r] - mx);
      m_run[r] = mx;
      float sum = 0.f;
#pragma unroll
      for (int j = 0; j < 8; ++j) {
        float p = __expf(sc[j][r] - mx);
        sc[j][r] = p;
        sum += p;
      }
      sum += __shfl_xor(sum, 1);
      sum += __shfl_xor(sum, 2);
      sum += __shfl_xor(sum, 4);
      sum += __shfl_xor(sum, 8);
      l_run[r] = l_run[r] * alpha + sum;
#pragma unroll
      for (int jv = 0; jv < 8; ++jv) Oacc[jv][r] *= alpha;
      // P write (wave-private region; visibility via the barrier below)
#pragma unroll
      for (int j = 0; j < 8; ++j)
        Psw[(fq * 4 + r) * 136 + j * 16 + fr] = f2b(sc[j][r]);
    }
    __syncthreads();  // drain V GLDS (Ps is wave-private, already visible)

    // ---- PV: O += P @ V^T ----
#pragma unroll
    for (int ks = 0; ks < 4; ++ks) {
      bf16x8 ap = *(const bf16x8*)(Psw + fr * 136 + ks * 32 + fq * 8);
#pragma unroll
      for (int jv = 0; jv < 8; ++jv) {
        const int vcol = jv * 16 + fr;
        bf16x8 vb = *(const bf16x8*)(Vs + vcol * 128 + (((ks * 4 + fq) ^ fr) * 8));
        Oacc[jv] = MFMA(ap, vb, Oacc[jv]);
      }
    }
    __syncthreads();  // protect Vs before next tile's stage
  }

  // ---- normalize + write ----
#pragma unroll
  for (int r = 0; r < 4; ++r) {
    const float inv = 1.0f / l_run[r];
    const long row = q0 + w * 16 + fq * 4 + r;
#pragma unroll
    for (int jv = 0; jv < 8; ++jv)
      ovb[row * 2048 + h * 128 + jv * 16 + fr] = f2b(Oacc[jv][r] * inv);
  }
}

// ---------------- conversion / transpose kernels ----------------
__global__ __launch_bounds__(256) void cast_bf16(const float* __restrict__ in,
                                                 u16* __restrict__ out, long n) {
  long i = ((long)blockIdx.x * 256 + threadIdx.x) * 4;
  if (i >= n) return;
  float4 v = *(const float4*)(in + i);
  ushort4 o = { f2b(v.x), f2b(v.y), f2b(v.z), f2b(v.w) };
  *(ushort4*)(out + i) = o;
}

__global__ __launch_bounds__(256) void transpose_cast(const float* __restrict__ in,
    u16* __restrict__ out, int ldi, int ldo, long sIn, long sOut) {
  in += (long)blockIdx.z * sIn;
  out += (long)blockIdx.z * sOut;
  __shared__ u16 t[32][33];
  const int i0 = blockIdx.y * 32, j0 = blockIdx.x * 32;
  const int tx = threadIdx.x & 31, ty = threadIdx.x >> 5;
  for (int r = ty; r < 32; r += 8)
    t[r][tx] = f2b(in[(long)(i0 + r) * ldi + j0 + tx]);
  __syncthreads();
  for (int r = ty; r < 32; r += 8)
    out[(long)(j0 + r) * ldo + i0 + tx] = t[tx][r];
}

// ---------------- RMSNorm fp32 -> bf16 ----------------
__global__ __launch_bounds__(256) void rmsnorm_cast(const float* __restrict__ in,
    const float* __restrict__ w, u16* __restrict__ out, int n) {
  __shared__ float red[4];
  const float* row = in + (long)blockIdx.x * n;
  u16* orow = out + (long)blockIdx.x * n;
  float ss = 0.f;
  for (int i = threadIdx.x; i < n; i += 256) { float v = row[i]; ss += v * v; }
  float tot = block_sum(ss, red);
  float inv = rsqrtf(tot / (float)n + 1e-6f);
  for (int i = threadIdx.x; i < n; i += 256) orow[i] = f2b(row[i] * inv * w[i]);
}

// ---------------- RoPE table (double precision) ----------------
__global__ void rope_table(float* tab) {
  int s = blockIdx.x, j = threadIdx.x;  // 32 threads
  double freq = pow(10000.0, -(double)j / 32.0);
  double ang = (double)s * freq;
  tab[s * 64 + j] = (float)cos(ang);
  tab[s * 64 + 32 + j] = (float)sin(ang);
}

// ---------------- k_full: rmsnorm(ckv) ++ rope(k_pe) -> bf16 ----------------
__global__ __launch_bounds__(256) void build_kfull(const float* __restrict__ ckv,
    const float* __restrict__ lnw, const float* __restrict__ tab, u16* __restrict__ kfb) {
  __shared__ float red[4];
  const int s = blockIdx.x;
  const float* row = ckv + (long)s * 640;  // padded ld
  float ss = 0.f;
  for (int i = threadIdx.x; i < 512; i += 256) { float v = row[i]; ss += v * v; }
  float tot = block_sum(ss, red);
  float inv = rsqrtf(tot / 512.0f + 1e-6f);
  u16* orow = kfb + (long)s * 576;
  for (int i = threadIdx.x; i < 512; i += 256) orow[i] = f2b(row[i] * inv * lnw[i]);
  if (threadIdx.x < 64) {
    int i = threadIdx.x, j = i & 31;
    float c = tab[s * 64 + j], sn = tab[s * 64 + 32 + j];
    float xv = row[512 + i];
    float rot = (i < 32) ? -row[512 + i + 32] : row[512 + i - 32];
    orow[512 + i] = f2b(xv * c + rot * sn);
  }
}

// ---------------- roped q_pe (bf16 in) into qfb[..., 512:576] ----------------
__global__ void rope_qpe(const u16* __restrict__ qb, const float* __restrict__ tab,
                         u16* __restrict__ qfb) {
  int s = blockIdx.x, h = blockIdx.y, i = threadIdx.x;  // 64 threads
  int j = i & 31;
  float c = tab[s * 64 + j], sn = tab[s * 64 + 32 + j];
  const u16* src = qb + (long)s * 3072 + h * 192 + 128;
  float xv = b2f(src[i]);
  float rot = (i < 32) ? -b2f(src[i + 32]) : b2f(src[i - 32]);
  qfb[(long)s * 9216 + h * 576 + 512 + i] = f2b(xv * c + rot * sn);
}

extern "C" void kernel_launch(void* const* d_in, const int* in_sizes, int n_in,
                              void* d_out, int out_size, void* d_ws, size_t ws_size,
                              hipStream_t stream) {
  const float* x      = (const float*)d_in[0];
  const float* w_q_a  = (const float*)d_in[1];
  const float* q_ln   = (const float*)d_in[2];
  const float* w_q_b  = (const float*)d_in[3];
  const float* w_kv_a = (const float*)d_in[4];
  const float* kv_ln  = (const float*)d_in[5];
  const float* w_kv_b = (const float*)d_in[6];
  const float* w_o    = (const float*)d_in[7];
  float* out = (float*)d_out;

  // ---- workspace layout (bytes) ----
  char* p = (char*)d_ws;
  float* tab   = (float*)p;  p += 524288;      // 2048*64 f32
  u16* wkvbb   = (u16*)p;    p += 4194304;     // 512*4096
  u16* wuvT    = (u16*)p;    p += 2097152;     // 16*128*512
  u16* woT     = (u16*)p;    p += 8388608;     // 2048*2048
  u16* qfb     = (u16*)p;    p += 37748736;    // 2048*9216
  u16* vallT   = (u16*)p;    p += 8388608;     // 16*128*2048
  u16* kfb     = (u16*)p;    p += 2359296;     // 2048*576
  u16* ovb     = (u16*)p;    p += 8388608;     // 2048*2048
  char* tb = p;                                // transient (phase-1 only)
  u16* xb      = (u16*)tb;                     // 2048*2048
  u16* wqaT    = (u16*)(tb + 8388608);         // 1536*2048
  float* qa    = (float*)(tb + 14680064);      // 2048*1536 f32
  u16* qab     = (u16*)(tb + 27262976);        // 2048*1536
  u16* wqbT    = (u16*)(tb + 33554432);        // 3072*1536
  u16* qb      = (u16*)(tb + 42991616);        // 2048*3072
  u16* wkvaT   = (u16*)(tb + 55574528);        // 640*2048 (pad rows unread)
  float* ckv   = (float*)(tb + 58195968);      // 2048*640 f32

  rope_table<<<dim3(2048), 32, 0, stream>>>(tab);

  // weight prep
  cast_bf16<<<4096, 256, 0, stream>>>(x, xb, 4194304);
  transpose_cast<<<dim3(48, 64), 256, 0, stream>>>(w_q_a, wqaT, 1536, 2048, 0, 0);
  transpose_cast<<<dim3(96, 48), 256, 0, stream>>>(w_q_b, wqbT, 3072, 1536, 0, 0);
  transpose_cast<<<dim3(18, 64), 256, 0, stream>>>(w_kv_a, wkvaT, 576, 2048, 0, 0);
  cast_bf16<<<2048, 256, 0, stream>>>(w_kv_b, wkvbb, 2097152);
  transpose_cast<<<dim3(4, 16, 16), 256, 0, stream>>>(w_kv_b + 128, wuvT, 4096, 512, 256, 65536);
  transpose_cast<<<dim3(64, 64), 256, 0, stream>>>(w_o, woT, 2048, 2048, 0, 0);

  // q_a = x @ w_q_a (f32 out), rmsnorm -> bf16
  gemm_mfma<0><<<dim3(12, 16), 256, 0, stream>>>(
      xb, wqaT, qa, 2048, 2048, 2048, 1536, 0, 0, 0);
  rmsnorm_cast<<<2048, 256, 0, stream>>>(qa, q_ln, qab, 1536);

  // q = q_a @ w_q_b (bf16 out)
  gemm_mfma<1><<<dim3(24, 16), 256, 0, stream>>>(
      qab, wqbT, qb, 1536, 1536, 1536, 3072, 0, 0, 0);

  // ckv_kpe = x @ w_kv_a (f32 out, ld 640); k_full -> bf16
  gemm_mfma<0><<<dim3(5, 16), 256, 0, stream>>>(
      xb, wkvaT, ckv, 2048, 2048, 2048, 640, 0, 0, 0);
  build_kfull<<<2048, 256, 0, stream>>>(ckv, kv_ln, tab, kfb);

  // q_full[:, h, :512] = q_nope[h] @ w_uk[h]^T (bf16 out, batched over h)
  gemm_mfma<1><<<dim3(4, 16, 16), 256, 0, stream>>>(
      qb, wkvbb, qfb, 128, 3072, 4096, 9216, 192, 256, 576);
  rope_qpe<<<dim3(2048, 16), 64, 0, stream>>>(qb, tab, qfb);

  // vallT[h] = (ckv_n @ w_uv[h])^T  (bf16 transposed out)
  gemm_mfma<2><<<dim3(1, 16, 16), 256, 0, stream>>>(
      kfb, wuvT, vallT, 512, 576, 512, 2048, 0, 65536, 262144);

  // fused flash attention v2 -> ovb
  attn_flash2<<<dim3(16, 32), 256, 0, stream>>>(qfb, kfb, vallT, ovb);

  // y = o_v @ w_o (f32 out)
  gemm_mfma<0><<<dim3(16, 16), 256, 0, stream>>>(
      ovb, woT, out, 2048, 2048, 2048, 2048, 0, 0, 0);
}

// Round 7
// 547.807 us; speedup vs baseline: 25.6723x; 1.0534x over previous
//
#include <hip/hip_runtime.h>
#include <math.h>

// DeepSeek V2 MLA attention — bf16 MFMA GEMMs + fused flash attention v3.
// v3: software-pipelined K-loops — triple-buffered LDS staging with raw
// s_barrier + explicit s_waitcnt vmcnt(N) (never 0 inside the loop), the
// AITER/hipBLASLt-style structure the plain __syncthreads() dbuf can't express.
// B=1 S=2048 E=2048 H=16 DN=128 DR=64 DV=128 R=512 QLR=1536

typedef unsigned short u16;
typedef unsigned int u32;
typedef __bf16 bf16x8 __attribute__((ext_vector_type(8)));
typedef float f32x4 __attribute__((ext_vector_type(4)));

__device__ __forceinline__ u16 f2b(float f) {  // fp32 -> bf16 RNE
  u32 u = __float_as_uint(f);
  u += 0x7FFFu + ((u >> 16) & 1u);
  return (u16)(u >> 16);
}
__device__ __forceinline__ float b2f(u16 v) {
  return __uint_as_float(((u32)v) << 16);
}

#define GLDS(g, l) __builtin_amdgcn_global_load_lds( \
    (const __attribute__((address_space(1))) u32*)(g), \
    (__attribute__((address_space(3))) u32*)(l), 16, 0, 0)

#define MFMA(a, b, c) __builtin_amdgcn_mfma_f32_16x16x32_bf16(a, b, c, 0, 0, 0)

// s_waitcnt vmcnt(N) (lgkmcnt/expcnt untouched) + s_barrier. No implicit
// vmcnt(0) drain — this is the whole point (m139-verified pattern).
template<int N>
__device__ __forceinline__ void vm_barrier() {
  __builtin_amdgcn_s_waitcnt(0xF70 | N);  // expcnt=7, lgkmcnt=15, vmcnt=N
  __builtin_amdgcn_s_barrier();
}

// ---------------- block reduction helper ----------------
__device__ __forceinline__ float block_sum(float v, float* red) {
#pragma unroll
  for (int off = 32; off > 0; off >>= 1) v += __shfl_down(v, off);
  const int lane = threadIdx.x & 63, w = threadIdx.x >> 6;
  if (lane == 0) red[w] = v;
  __syncthreads();
  float r = red[0] + red[1] + red[2] + red[3];
  __syncthreads();
  return r;
}

// ---------------- bf16 MFMA GEMM, 128x128 tile, BK=32, pipelined ------------
// C = A[M,K] @ B[N,K]^T (both row-major bf16). Batched over blockIdx.z.
// OUTK: 0 = fp32 out, 1 = bf16 out, 2 = bf16 transposed out (C[n*ldc+m]).
// Requires K/32 >= 2.
template<int OUTK>
__global__ __launch_bounds__(256) void gemm_mfma(
    const u16* __restrict__ A, const u16* __restrict__ B, void* __restrict__ Cv,
    int K, int lda, int ldb, int ldc, long sA, long sB, long sC)
{
  __shared__ u16 At[3][4096];  // 24 KB: 128 rows x 32 k, triple-buffered
  __shared__ u16 Bt[3][4096];  // 24 KB
  const u16* Ab = A + (long)blockIdx.z * sA;
  const u16* Bb = B + (long)blockIdx.z * sB;
  const int tid = threadIdx.x;
  const int w = tid >> 6, lane = tid & 63;
  const int m0 = blockIdx.y * 128, n0 = blockIdx.x * 128;
  const int wm = (w >> 1) * 64, wn = (w & 1) * 64;
  const int fr = lane & 15, fq = lane >> 4;

  const int c0 = w * 2, c1 = w * 2 + 1;
  const int e0 = (c0 * 64 + lane) * 8, e1 = (c1 * 64 + lane) * 8;
  const int r0 = e0 >> 5, col0 = e0 & 31;
  const int r1 = e1 >> 5, col1 = e1 & 31;

  const int nk = K >> 5;
  auto issue = [&](int kc) {
    const int k0 = kc * 32;
    u16* at = At[kc % 3];
    u16* bt = Bt[kc % 3];
    GLDS(Ab + (long)(m0 + r0) * lda + k0 + col0, at + c0 * 512);
    GLDS(Bb + (long)(n0 + r0) * ldb + k0 + col0, bt + c0 * 512);
    GLDS(Ab + (long)(m0 + r1) * lda + k0 + col1, at + c1 * 512);
    GLDS(Bb + (long)(n0 + r1) * ldb + k0 + col1, bt + c1 * 512);
  };

  f32x4 acc[4][4] = {};
  issue(0);
  issue(1);
  vm_barrier<4>();  // chunk 0 landed; chunk 1's 4 still in flight
  for (int kc = 0; kc < nk; ++kc) {
    if (kc + 2 < nk) issue(kc + 2);
    const u16* at = At[kc % 3];
    const u16* bt = Bt[kc % 3];
    bf16x8 af[4], bfr[4];
#pragma unroll
    for (int i = 0; i < 4; ++i)
      af[i] = *(const bf16x8*)(at + (wm + i * 16 + fr) * 32 + fq * 8);
#pragma unroll
    for (int j = 0; j < 4; ++j)
      bfr[j] = *(const bf16x8*)(bt + (wn + j * 16 + fr) * 32 + fq * 8);
#pragma unroll
    for (int i = 0; i < 4; ++i)
#pragma unroll
      for (int j = 0; j < 4; ++j)
        acc[i][j] = MFMA(af[i], bfr[j], acc[i][j]);
    if (kc + 1 < nk) {
      if (kc + 2 < nk) vm_barrier<4>();  // chunk kc+1 ready; kc+2 in flight
      else vm_barrier<0>();              // nothing newer — full wait
    }
  }

  // D mapping (verified m89/m91): col = lane&15, row = (lane>>4)*4 + reg.
  if (OUTK == 0) {
    float* C = (float*)Cv + (long)blockIdx.z * sC;
#pragma unroll
    for (int i = 0; i < 4; ++i)
#pragma unroll
      for (int j = 0; j < 4; ++j) {
        long base = (long)(m0 + wm + i * 16 + fq * 4) * ldc + (n0 + wn + j * 16 + fr);
#pragma unroll
        for (int r = 0; r < 4; ++r) C[base + (long)r * ldc] = acc[i][j][r];
      }
  } else if (OUTK == 1) {
    u16* C = (u16*)Cv + (long)blockIdx.z * sC;
#pragma unroll
    for (int i = 0; i < 4; ++i)
#pragma unroll
      for (int j = 0; j < 4; ++j) {
        long base = (long)(m0 + wm + i * 16 + fq * 4) * ldc + (n0 + wn + j * 16 + fr);
#pragma unroll
        for (int r = 0; r < 4; ++r) C[base + (long)r * ldc] = f2b(acc[i][j][r]);
      }
  } else {
    u16* C = (u16*)Cv + (long)blockIdx.z * sC;
#pragma unroll
    for (int i = 0; i < 4; ++i)
#pragma unroll
      for (int j = 0; j < 4; ++j) {
        ushort4 v = { f2b(acc[i][j][0]), f2b(acc[i][j][1]),
                      f2b(acc[i][j][2]), f2b(acc[i][j][3]) };
        *(ushort4*)(C + (long)(n0 + wn + j * 16 + fr) * ldc + (m0 + wm + i * 16 + fq * 4)) = v;
      }
  }
}

// ---------------- fused flash attention v3 (pipelined) ----------------
// grid (16 heads, 32 q-tiles of 64 rows), 256 threads.
// Wave w owns q-rows [q0+16w, q0+16w+16) x all 128 k-cols of each K-tile.
// Q A-frags resident in registers; K triple-buffered w/ vmcnt(2) barriers;
// V staged via GLDS overlapped with softmax; wave-local online softmax.
__global__ __launch_bounds__(256, 2) void attn_flash2(
    const u16* __restrict__ qfb,   // [2048][16*576]
    const u16* __restrict__ kfb,   // [2048][576]
    const u16* __restrict__ vallT, // [16][128][2048]  (v-col major)
    u16* __restrict__ ovb)         // [2048][2048]
{
  __shared__ u16 Ks[3][4096];    // 24 KB: K chunks, [row 128][g'=g^(row&3)][8]
  __shared__ u16 Vs[16384];      // 32 KB: [vcol 128][s: holds g=s^(vcol&15)][8]
  __shared__ u16 Ps[4 * 2176];   // 17 KB: per-wave P, 16 rows x 136 stride

  const int h = blockIdx.x;
  const int y = blockIdx.y;
  const int qt = (y & 1) ? (y >> 1) : (31 - (y >> 1));  // pair heavy+light
  const int q0 = qt * 64;
  const int tid = threadIdx.x;
  const int w = tid >> 6, lane = tid & 63;
  const int fr = lane & 15, fq = lane >> 4;
  const float scale = 0.07216878364870323f;  // (DN+DR)^-0.5
  const int ktiles = (qt >> 1) + 1;
  u16* Psw = Ps + w * 2176;

  // ---- Q fragments, resident (A[m=lane&15=fr][k=fq*8+j]) ----
  bf16x8 aq[18];
  {
    const u16* qp = qfb + (long)(q0 + w * 16 + fr) * 9216 + h * 576 + fq * 8;
#pragma unroll
    for (int d = 0; d < 18; ++d) aq[d] = *(const bf16x8*)(qp + d * 32);
  }

  // K staging coords: instr i=w*2+c covers LDS bytes [i*1024, i*1024+1024)
  const int krow0 = (w * 2) * 16 + (lane >> 2);
  const int krow1 = (w * 2 + 1) * 16 + (lane >> 2);
  const int kg0 = (lane & 3) ^ (krow0 & 3);
  const int kg1 = (lane & 3) ^ (krow1 & 3);
  // V staging coords: instr i=w*8+c covers vcols [i*4, i*4+4); 32 instrs total
  const int vlanecol = lane >> 4;
  const int vslot = lane & 15;

  float m_run[4], l_run[4];
#pragma unroll
  for (int r = 0; r < 4; ++r) { m_run[r] = -1e30f; l_run[r] = 0.f; }
  f32x4 Oacc[8] = {};
  const u16* vbase = vallT + (long)h * 262144;

  for (int kt = 0; kt < ktiles; ++kt) {
    const int k0 = kt * 128;
    auto issueK = [&](int c) {
      const int d0 = c * 32;
      u16* dst = Ks[c % 3];
      GLDS(kfb + (long)(k0 + krow0) * 576 + d0 + kg0 * 8, dst + (w * 2) * 512);
      GLDS(kfb + (long)(k0 + krow1) * 576 + d0 + kg1 * 8, dst + (w * 2 + 1) * 512);
    };

    // ---- QK^T: 18 pipelined BK=32 steps, vmcnt(2) barriers ----
    issueK(0);
    issueK(1);
    vm_barrier<2>();  // chunk 0 landed; chunk 1's 2 in flight
    f32x4 sc[8] = {};
#pragma unroll
    for (int d = 0; d < 18; ++d) {
      if (d + 2 < 18) issueK(d + 2);
      const u16* kb = Ks[d % 3];
#pragma unroll
      for (int j = 0; j < 8; ++j) {
        const int row = j * 16 + fr;
        bf16x8 b = *(const bf16x8*)(kb + row * 32 + ((fq ^ (row & 3)) * 8));
        sc[j] = MFMA(aq[d], b, sc[j]);
      }
      if (d < 17) {
        if (d + 2 < 18) vm_barrier<2>();
        else vm_barrier<0>();
      }
    }

    // ---- issue V stage: 8 GLDS/wave, 32 total -> all 128 vcols ----
#pragma unroll
    for (int c = 0; c < 8; ++c) {
      const int i = w * 8 + c;
      const int vcol = i * 4 + vlanecol;
      const int g = vslot ^ (vcol & 15);
      GLDS(vbase + (long)vcol * 2048 + k0 + g * 8, Vs + i * 512);
    }

    // ---- wave-local online softmax (hides V load latency) ----
    const bool diag = (kt == ktiles - 1);
#pragma unroll
    for (int r = 0; r < 4; ++r) {
      float mx = m_run[r];
#pragma unroll
      for (int j = 0; j < 8; ++j) {
        float s = sc[j][r] * scale;
        if (diag) {
          const int row = q0 + w * 16 + fq * 4 + r;
          const int col = k0 + j * 16 + fr;
          if (col > row) s = -1e30f;
        }
        sc[j][r] = s;
        mx = fmaxf(mx, s);
      }
      mx = fmaxf(mx, __shfl_xor(mx, 1));
      mx = fmaxf(mx, __shfl_xor(mx, 2));
      mx = fmaxf(mx, __shfl_xor(mx, 4));
      mx = fmaxf(mx, __shfl_xor(mx, 8));
      const float alpha = __expf(m_run[r] - mx);
      m_run[r] = mx;
      float sum = 0.f;
#pragma unroll
      for (int j = 0; j < 8; ++j) {
        float p = __expf(sc[j][r] - mx);
        sc[j][r] = p;
        sum += p;
      }
      sum += __shfl_xor(sum, 1);
      sum += __shfl_xor(sum, 2);
      sum += __shfl_xor(sum, 4);
      sum += __shfl_xor(sum, 8);
      l_run[r] = l_run[r] * alpha + sum;
#pragma unroll
      for (int jv = 0; jv < 8; ++jv) Oacc[jv][r] *= alpha;
      // P write (wave-private region)
#pragma unroll
      for (int j = 0; j < 8; ++j)
        Psw[(fq * 4 + r) * 136 + j * 16 + fr] = f2b(sc[j][r]);
    }
    vm_barrier<0>();  // V landed, visible to all waves

    // ---- PV: O += P @ V^T ----
#pragma unroll
    for (int ks = 0; ks < 4; ++ks) {
      bf16x8 ap = *(const bf16x8*)(Psw + fr * 136 + ks * 32 + fq * 8);
#pragma unroll
      for (int jv = 0; jv < 8; ++jv) {
        const int vcol = jv * 16 + fr;
        bf16x8 vb = *(const bf16x8*)(Vs + vcol * 128 + (((ks * 4 + fq) ^ fr) * 8));
        Oacc[jv] = MFMA(ap, vb, Oacc[jv]);
      }
    }
    __builtin_amdgcn_s_barrier();  // Vs/Ks reads done -> next tile may restage
  }

  // ---- normalize + write ----
#pragma unroll
  for (int r = 0; r < 4; ++r) {
    const float inv = 1.0f / l_run[r];
    const long row = q0 + w * 16 + fq * 4 + r;
#pragma unroll
    for (int jv = 0; jv < 8; ++jv)
      ovb[row * 2048 + h * 128 + jv * 16 + fr] = f2b(Oacc[jv][r] * inv);
  }
}

// ---------------- conversion / transpose kernels ----------------
__global__ __launch_bounds__(256) void cast_bf16(const float* __restrict__ in,
                                                 u16* __restrict__ out, long n) {
  long i = ((long)blockIdx.x * 256 + threadIdx.x) * 4;
  if (i >= n) return;
  float4 v = *(const float4*)(in + i);
  ushort4 o = { f2b(v.x), f2b(v.y), f2b(v.z), f2b(v.w) };
  *(ushort4*)(out + i) = o;
}

__global__ __launch_bounds__(256) void transpose_cast(const float* __restrict__ in,
    u16* __restrict__ out, int ldi, int ldo, long sIn, long sOut) {
  in += (long)blockIdx.z * sIn;
  out += (long)blockIdx.z * sOut;
  __shared__ u16 t[32][33];
  const int i0 = blockIdx.y * 32, j0 = blockIdx.x * 32;
  const int tx = threadIdx.x & 31, ty = threadIdx.x >> 5;
  for (int r = ty; r < 32; r += 8)
    t[r][tx] = f2b(in[(long)(i0 + r) * ldi + j0 + tx]);
  __syncthreads();
  for (int r = ty; r < 32; r += 8)
    out[(long)(j0 + r) * ldo + i0 + tx] = t[tx][r];
}

// ---------------- RMSNorm fp32 -> bf16 ----------------
__global__ __launch_bounds__(256) void rmsnorm_cast(const float* __restrict__ in,
    const float* __restrict__ w, u16* __restrict__ out, int n) {
  __shared__ float red[4];
  const float* row = in + (long)blockIdx.x * n;
  u16* orow = out + (long)blockIdx.x * n;
  float ss = 0.f;
  for (int i = threadIdx.x; i < n; i += 256) { float v = row[i]; ss += v * v; }
  float tot = block_sum(ss, red);
  float inv = rsqrtf(tot / (float)n + 1e-6f);
  for (int i = threadIdx.x; i < n; i += 256) orow[i] = f2b(row[i] * inv * w[i]);
}

// ---------------- RoPE table (double precision) ----------------
__global__ __launch_bounds__(256) void rope_table(float* tab) {
  int s = blockIdx.x * 8 + (threadIdx.x >> 5), j = threadIdx.x & 31;
  double freq = pow(10000.0, -(double)j / 32.0);
  double ang = (double)s * freq;
  tab[s * 64 + j] = (float)cos(ang);
  tab[s * 64 + 32 + j] = (float)sin(ang);
}

// ---------------- k_full: rmsnorm(ckv) ++ rope(k_pe) -> bf16 ----------------
__global__ __launch_bounds__(256) void build_kfull(const float* __restrict__ ckv,
    const float* __restrict__ lnw, const float* __restrict__ tab, u16* __restrict__ kfb) {
  __shared__ float red[4];
  const int s = blockIdx.x;
  const float* row = ckv + (long)s * 640;  // padded ld
  float ss = 0.f;
  for (int i = threadIdx.x; i < 512; i += 256) { float v = row[i]; ss += v * v; }
  float tot = block_sum(ss, red);
  float inv = rsqrtf(tot / 512.0f + 1e-6f);
  u16* orow = kfb + (long)s * 576;
  for (int i = threadIdx.x; i < 512; i += 256) orow[i] = f2b(row[i] * inv * lnw[i]);
  if (threadIdx.x < 64) {
    int i = threadIdx.x, j = i & 31;
    float c = tab[s * 64 + j], sn = tab[s * 64 + 32 + j];
    float xv = row[512 + i];
    float rot = (i < 32) ? -row[512 + i + 32] : row[512 + i - 32];
    orow[512 + i] = f2b(xv * c + rot * sn);
  }
}

// ---------------- roped q_pe (bf16 in) into qfb[..., 512:576] ----------------
__global__ void rope_qpe(const u16* __restrict__ qb, const float* __restrict__ tab,
                         u16* __restrict__ qfb) {
  int s = blockIdx.x, h = blockIdx.y, i = threadIdx.x;  // 64 threads
  int j = i & 31;
  float c = tab[s * 64 + j], sn = tab[s * 64 + 32 + j];
  const u16* src = qb + (long)s * 3072 + h * 192 + 128;
  float xv = b2f(src[i]);
  float rot = (i < 32) ? -b2f(src[i + 32]) : b2f(src[i - 32]);
  qfb[(long)s * 9216 + h * 576 + 512 + i] = f2b(xv * c + rot * sn);
}

extern "C" void kernel_launch(void* const* d_in, const int* in_sizes, int n_in,
                              void* d_out, int out_size, void* d_ws, size_t ws_size,
                              hipStream_t stream) {
  const float* x      = (const float*)d_in[0];
  const float* w_q_a  = (const float*)d_in[1];
  const float* q_ln   = (const float*)d_in[2];
  const float* w_q_b  = (const float*)d_in[3];
  const float* w_kv_a = (const float*)d_in[4];
  const float* kv_ln  = (const float*)d_in[5];
  const float* w_kv_b = (const float*)d_in[6];
  const float* w_o    = (const float*)d_in[7];
  float* out = (float*)d_out;

  // ---- workspace layout (bytes) ----
  char* p = (char*)d_ws;
  float* tab   = (float*)p;  p += 524288;      // 2048*64 f32
  u16* wkvbb   = (u16*)p;    p += 4194304;     // 512*4096
  u16* wuvT    = (u16*)p;    p += 2097152;     // 16*128*512
  u16* woT     = (u16*)p;    p += 8388608;     // 2048*2048
  u16* qfb     = (u16*)p;    p += 37748736;    // 2048*9216
  u16* vallT   = (u16*)p;    p += 8388608;     // 16*128*2048
  u16* kfb     = (u16*)p;    p += 2359296;     // 2048*576
  u16* ovb     = (u16*)p;    p += 8388608;     // 2048*2048
  char* tb = p;                                // transient (phase-1 only)
  u16* xb      = (u16*)tb;                     // 2048*2048
  u16* wqaT    = (u16*)(tb + 8388608);         // 1536*2048
  float* qa    = (float*)(tb + 14680064);      // 2048*1536 f32
  u16* qab     = (u16*)(tb + 27262976);        // 2048*1536
  u16* wqbT    = (u16*)(tb + 33554432);        // 3072*1536
  u16* qb      = (u16*)(tb + 42991616);        // 2048*3072
  u16* wkvaT   = (u16*)(tb + 55574528);        // 640*2048 (pad rows unread)
  float* ckv   = (float*)(tb + 58195968);      // 2048*640 f32

  rope_table<<<dim3(256), 256, 0, stream>>>(tab);

  // weight prep
  cast_bf16<<<4096, 256, 0, stream>>>(x, xb, 4194304);
  transpose_cast<<<dim3(48, 64), 256, 0, stream>>>(w_q_a, wqaT, 1536, 2048, 0, 0);
  transpose_cast<<<dim3(96, 48), 256, 0, stream>>>(w_q_b, wqbT, 3072, 1536, 0, 0);
  transpose_cast<<<dim3(18, 64), 256, 0, stream>>>(w_kv_a, wkvaT, 576, 2048, 0, 0);
  cast_bf16<<<2048, 256, 0, stream>>>(w_kv_b, wkvbb, 2097152);
  transpose_cast<<<dim3(4, 16, 16), 256, 0, stream>>>(w_kv_b + 128, wuvT, 4096, 512, 256, 65536);
  transpose_cast<<<dim3(64, 64), 256, 0, stream>>>(w_o, woT, 2048, 2048, 0, 0);

  // q_a = x @ w_q_a (f32 out), rmsnorm -> bf16
  gemm_mfma<0><<<dim3(12, 16), 256, 0, stream>>>(
      xb, wqaT, qa, 2048, 2048, 2048, 1536, 0, 0, 0);
  rmsnorm_cast<<<2048, 256, 0, stream>>>(qa, q_ln, qab, 1536);

  // q = q_a @ w_q_b (bf16 out)
  gemm_mfma<1><<<dim3(24, 16), 256, 0, stream>>>(
      qab, wqbT, qb, 1536, 1536, 1536, 3072, 0, 0, 0);

  // ckv_kpe = x @ w_kv_a (f32 out, ld 640); k_full -> bf16
  gemm_mfma<0><<<dim3(5, 16), 256, 0, stream>>>(
      xb, wkvaT, ckv, 2048, 2048, 2048, 640, 0, 0, 0);
  build_kfull<<<2048, 256, 0, stream>>>(ckv, kv_ln, tab, kfb);

  // q_full[:, h, :512] = q_nope[h] @ w_uk[h]^T (bf16 out, batched over h)
  gemm_mfma<1><<<dim3(4, 16, 16), 256, 0, stream>>>(
      qb, wkvbb, qfb, 128, 3072, 4096, 9216, 192, 256, 576);
  rope_qpe<<<dim3(2048, 16), 64, 0, stream>>>(qb, tab, qfb);

  // vallT[h] = (ckv_n @ w_uv[h])^T  (bf16 transposed out)
  gemm_mfma<2><<<dim3(1, 16, 16), 256, 0, stream>>>(
      kfb, wuvT, vallT, 512, 576, 512, 2048, 0, 65536, 262144);

  // fused flash attention v3 -> ovb
  attn_flash2<<<dim3(16, 32), 256, 0, stream>>>(qfb, kfb, vallT, ovb);

  // y = o_v @ w_o (f32 out)
  gemm_mfma<0><<<dim3(16, 16), 256, 0, stream>>>(
      ovb, woT, out, 2048, 2048, 2048, 2048, 0, 0, 0);
}

// Round 8
// 477.051 us; speedup vs baseline: 29.4799x; 1.1483x over previous
//
#include <hip/hip_runtime.h>
#include <math.h>

// DeepSeek V2 MLA attention — bf16 MFMA GEMMs + split-K flash attention with
// a dynamic work queue (v4). Attention work items (h, q-tile, k-chunk<=4
// ktiles) are popped from a global atomic counter heavy-first, so load
// balance holds under ANY block->CU assignment; partials are merged by a
// small log-sum-exp reduce kernel.
// B=1 S=2048 E=2048 H=16 DN=128 DR=64 DV=128 R=512 QLR=1536

typedef unsigned short u16;
typedef unsigned int u32;
typedef __bf16 bf16x8 __attribute__((ext_vector_type(8)));
typedef float f32x4 __attribute__((ext_vector_type(4)));
typedef unsigned short u16x8 __attribute__((ext_vector_type(8)));

__device__ __forceinline__ u16 f2b(float f) {  // fp32 -> bf16 RNE
  u32 u = __float_as_uint(f);
  u += 0x7FFFu + ((u >> 16) & 1u);
  return (u16)(u >> 16);
}
__device__ __forceinline__ float b2f(u16 v) {
  return __uint_as_float(((u32)v) << 16);
}

#define GLDS(g, l) __builtin_amdgcn_global_load_lds( \
    (const __attribute__((address_space(1))) u32*)(g), \
    (__attribute__((address_space(3))) u32*)(l), 16, 0, 0)

#define MFMA(a, b, c) __builtin_amdgcn_mfma_f32_16x16x32_bf16(a, b, c, 0, 0, 0)

// s_waitcnt vmcnt(N) (lgkmcnt/expcnt untouched) + s_barrier.
template<int N>
__device__ __forceinline__ void vm_barrier() {
  __builtin_amdgcn_s_waitcnt(0xF70 | N);  // expcnt=7, lgkmcnt=15, vmcnt=N
  __builtin_amdgcn_s_barrier();
}

// items enumerated qt-descending (heavy first): for qt=31..0, kc=0..nkc-1,
// h=0..15.  nkc(qt) = ceil((qt/2+1)/4).  Total = 1280.
#define N_ITEMS 1280
__device__ __forceinline__ int nkc_of(int qt) { return (((qt >> 1) + 1) + 3) >> 2; }

// ---------------- block reduction helper ----------------
__device__ __forceinline__ float block_sum(float v, float* red) {
#pragma unroll
  for (int off = 32; off > 0; off >>= 1) v += __shfl_down(v, off);
  const int lane = threadIdx.x & 63, w = threadIdx.x >> 6;
  if (lane == 0) red[w] = v;
  __syncthreads();
  float r = red[0] + red[1] + red[2] + red[3];
  __syncthreads();
  return r;
}

// ---------------- bf16 MFMA GEMM, 128x128 tile, BK=32, pipelined ------------
// C = A[M,K] @ B[N,K]^T (both row-major bf16). Batched over blockIdx.z.
// OUTK: 0 = fp32 out, 1 = bf16 out, 2 = bf16 transposed out (C[n*ldc+m]).
template<int OUTK>
__global__ __launch_bounds__(256) void gemm_mfma(
    const u16* __restrict__ A, const u16* __restrict__ B, void* __restrict__ Cv,
    int K, int lda, int ldb, int ldc, long sA, long sB, long sC)
{
  __shared__ u16 At[3][4096];  // triple-buffered 128x32 tiles
  __shared__ u16 Bt[3][4096];
  const u16* Ab = A + (long)blockIdx.z * sA;
  const u16* Bb = B + (long)blockIdx.z * sB;
  const int tid = threadIdx.x;
  const int w = tid >> 6, lane = tid & 63;
  const int m0 = blockIdx.y * 128, n0 = blockIdx.x * 128;
  const int wm = (w >> 1) * 64, wn = (w & 1) * 64;
  const int fr = lane & 15, fq = lane >> 4;

  const int c0 = w * 2, c1 = w * 2 + 1;
  const int e0 = (c0 * 64 + lane) * 8, e1 = (c1 * 64 + lane) * 8;
  const int r0 = e0 >> 5, col0 = e0 & 31;
  const int r1 = e1 >> 5, col1 = e1 & 31;

  const int nk = K >> 5;
  auto issue = [&](int kc) {
    const int k0 = kc * 32;
    u16* at = At[kc % 3];
    u16* bt = Bt[kc % 3];
    GLDS(Ab + (long)(m0 + r0) * lda + k0 + col0, at + c0 * 512);
    GLDS(Bb + (long)(n0 + r0) * ldb + k0 + col0, bt + c0 * 512);
    GLDS(Ab + (long)(m0 + r1) * lda + k0 + col1, at + c1 * 512);
    GLDS(Bb + (long)(n0 + r1) * ldb + k0 + col1, bt + c1 * 512);
  };

  f32x4 acc[4][4] = {};
  issue(0);
  issue(1);
  vm_barrier<4>();
  for (int kc = 0; kc < nk; ++kc) {
    if (kc + 2 < nk) issue(kc + 2);
    const u16* at = At[kc % 3];
    const u16* bt = Bt[kc % 3];
    bf16x8 af[4], bfr[4];
#pragma unroll
    for (int i = 0; i < 4; ++i)
      af[i] = *(const bf16x8*)(at + (wm + i * 16 + fr) * 32 + fq * 8);
#pragma unroll
    for (int j = 0; j < 4; ++j)
      bfr[j] = *(const bf16x8*)(bt + (wn + j * 16 + fr) * 32 + fq * 8);
#pragma unroll
    for (int i = 0; i < 4; ++i)
#pragma unroll
      for (int j = 0; j < 4; ++j)
        acc[i][j] = MFMA(af[i], bfr[j], acc[i][j]);
    if (kc + 1 < nk) {
      if (kc + 2 < nk) vm_barrier<4>();
      else vm_barrier<0>();
    }
  }

  if (OUTK == 0) {
    float* C = (float*)Cv + (long)blockIdx.z * sC;
#pragma unroll
    for (int i = 0; i < 4; ++i)
#pragma unroll
      for (int j = 0; j < 4; ++j) {
        long base = (long)(m0 + wm + i * 16 + fq * 4) * ldc + (n0 + wn + j * 16 + fr);
#pragma unroll
        for (int r = 0; r < 4; ++r) C[base + (long)r * ldc] = acc[i][j][r];
      }
  } else if (OUTK == 1) {
    u16* C = (u16*)Cv + (long)blockIdx.z * sC;
#pragma unroll
    for (int i = 0; i < 4; ++i)
#pragma unroll
      for (int j = 0; j < 4; ++j) {
        long base = (long)(m0 + wm + i * 16 + fq * 4) * ldc + (n0 + wn + j * 16 + fr);
#pragma unroll
        for (int r = 0; r < 4; ++r) C[base + (long)r * ldc] = f2b(acc[i][j][r]);
      }
  } else {
    u16* C = (u16*)Cv + (long)blockIdx.z * sC;
#pragma unroll
    for (int i = 0; i < 4; ++i)
#pragma unroll
      for (int j = 0; j < 4; ++j) {
        ushort4 v = { f2b(acc[i][j][0]), f2b(acc[i][j][1]),
                      f2b(acc[i][j][2]), f2b(acc[i][j][3]) };
        *(ushort4*)(C + (long)(n0 + wn + j * 16 + fr) * ldc + (m0 + wm + i * 16 + fq * 4)) = v;
      }
  }
}

// ---------------- counter init ----------------
__global__ void init_ctr(u32* ctr) { *ctr = 0; }

// ---------------- split-K flash attention, dynamic queue ----------------
// 512 persistent blocks pop items (h, qt, kc). Item = q-rows [qt*64,+64) of
// head h vs K-tiles [4kc, min(4kc+4, ktt)). Writes raw-O partial (bf16) +
// per-row (m, l) stats; reduce kernel combines.
__global__ __launch_bounds__(256, 2) void attn_partial(
    const u16* __restrict__ qfb,   // [2048][16*576]
    const u16* __restrict__ kfb,   // [2048][576]
    const u16* __restrict__ vallT, // [16][128][2048]
    u32* __restrict__ ctr,
    u16* __restrict__ pO,          // [N_ITEMS][64][128]
    float* __restrict__ pS)        // [N_ITEMS][64][2]
{
  __shared__ u16 Ks[3][4096];    // K chunks, [row 128][g'=g^(row&3)][8]
  __shared__ u16 Vs[16384];      // [vcol 128][s: holds g=s^(vcol&15)][8]
  __shared__ u16 Ps[4 * 2176];   // per-wave P, 16 rows x 136 stride
  __shared__ u32 cur;

  const int tid = threadIdx.x;
  const int w = tid >> 6, lane = tid & 63;
  const int fr = lane & 15, fq = lane >> 4;
  const float scale = 0.07216878364870323f;  // (DN+DR)^-0.5
  u16* Psw = Ps + w * 2176;

  const int krow0 = (w * 2) * 16 + (lane >> 2);
  const int krow1 = (w * 2 + 1) * 16 + (lane >> 2);
  const int kg0 = (lane & 3) ^ (krow0 & 3);
  const int kg1 = (lane & 3) ^ (krow1 & 3);
  const int vlanecol = lane >> 4;
  const int vslot = lane & 15;

  while (true) {
    if (tid == 0) cur = atomicAdd(ctr, 1u);
    __syncthreads();
    const u32 it = cur;
    if (it >= N_ITEMS) break;

    // decode (qt descending, kc asc, h asc)
    int rem = (int)it, qt = 31, kc = 0, h = 0;
    for (int q = 31; q >= 0; --q) {
      int cnt = nkc_of(q) * 16;
      if (rem < cnt) { qt = q; kc = rem >> 4; h = rem & 15; break; }
      rem -= cnt;
    }
    const int q0 = qt * 64;
    const int ktt = (qt >> 1) + 1;
    const int kt0 = kc * 4, kt1 = min(kt0 + 4, ktt);

    // Q fragments resident (A[m=fr][k=fq*8+j])
    bf16x8 aq[18];
    {
      const u16* qp = qfb + (long)(q0 + w * 16 + fr) * 9216 + h * 576 + fq * 8;
#pragma unroll
      for (int d = 0; d < 18; ++d) aq[d] = *(const bf16x8*)(qp + d * 32);
    }

    float m_run[4], l_run[4];
#pragma unroll
    for (int r = 0; r < 4; ++r) { m_run[r] = -1e30f; l_run[r] = 0.f; }
    f32x4 Oacc[8] = {};
    const u16* vbase = vallT + (long)h * 262144;

    for (int kt = kt0; kt < kt1; ++kt) {
      const int k0 = kt * 128;
      auto issueK = [&](int c) {
        const int d0 = c * 32;
        u16* dst = Ks[c % 3];
        GLDS(kfb + (long)(k0 + krow0) * 576 + d0 + kg0 * 8, dst + (w * 2) * 512);
        GLDS(kfb + (long)(k0 + krow1) * 576 + d0 + kg1 * 8, dst + (w * 2 + 1) * 512);
      };

      issueK(0);
      issueK(1);
      vm_barrier<2>();  // Q + chunk0 landed; chunk1 in flight
      f32x4 sc[8] = {};
#pragma unroll
      for (int d = 0; d < 18; ++d) {
        if (d + 2 < 18) issueK(d + 2);
        const u16* kb = Ks[d % 3];
#pragma unroll
        for (int j = 0; j < 8; ++j) {
          const int row = j * 16 + fr;
          bf16x8 b = *(const bf16x8*)(kb + row * 32 + ((fq ^ (row & 3)) * 8));
          sc[j] = MFMA(aq[d], b, sc[j]);
        }
        if (d < 17) {
          if (d + 2 < 18) vm_barrier<2>();
          else vm_barrier<0>();
        }
      }

      // V stage: 8 GLDS/wave (latency hidden by softmax)
#pragma unroll
      for (int c = 0; c < 8; ++c) {
        const int i = w * 8 + c;
        const int vcol = i * 4 + vlanecol;
        const int g = vslot ^ (vcol & 15);
        GLDS(vbase + (long)vcol * 2048 + k0 + g * 8, Vs + i * 512);
      }

      // wave-local online softmax
      const bool diag = (kt == ktt - 1);
#pragma unroll
      for (int r = 0; r < 4; ++r) {
        float mx = m_run[r];
#pragma unroll
        for (int j = 0; j < 8; ++j) {
          float s = sc[j][r] * scale;
          if (diag) {
            const int row = q0 + w * 16 + fq * 4 + r;
            const int col = k0 + j * 16 + fr;
            if (col > row) s = -1e30f;
          }
          sc[j][r] = s;
          mx = fmaxf(mx, s);
        }
        mx = fmaxf(mx, __shfl_xor(mx, 1));
        mx = fmaxf(mx, __shfl_xor(mx, 2));
        mx = fmaxf(mx, __shfl_xor(mx, 4));
        mx = fmaxf(mx, __shfl_xor(mx, 8));
        const float alpha = __expf(m_run[r] - mx);
        m_run[r] = mx;
        float sum = 0.f;
#pragma unroll
        for (int j = 0; j < 8; ++j) {
          float p = __expf(sc[j][r] - mx);
          sc[j][r] = p;
          sum += p;
        }
        sum += __shfl_xor(sum, 1);
        sum += __shfl_xor(sum, 2);
        sum += __shfl_xor(sum, 4);
        sum += __shfl_xor(sum, 8);
        l_run[r] = l_run[r] * alpha + sum;
#pragma unroll
        for (int jv = 0; jv < 8; ++jv) Oacc[jv][r] *= alpha;
#pragma unroll
        for (int j = 0; j < 8; ++j)
          Psw[(fq * 4 + r) * 136 + j * 16 + fr] = f2b(sc[j][r]);
      }
      vm_barrier<0>();  // V landed

      // PV: O += P @ V^T
#pragma unroll
      for (int ks = 0; ks < 4; ++ks) {
        bf16x8 ap = *(const bf16x8*)(Psw + fr * 136 + ks * 32 + fq * 8);
#pragma unroll
        for (int jv = 0; jv < 8; ++jv) {
          const int vcol = jv * 16 + fr;
          bf16x8 vb = *(const bf16x8*)(Vs + vcol * 128 + (((ks * 4 + fq) ^ fr) * 8));
          Oacc[jv] = MFMA(ap, vb, Oacc[jv]);
        }
      }
      __builtin_amdgcn_s_barrier();  // protect Ks/Vs before next stage
    }

    // write partial: raw O (bf16) + per-row stats
    const long po = (long)it * 8192;
#pragma unroll
    for (int r = 0; r < 4; ++r) {
      const int lr = w * 16 + fq * 4 + r;
      if (fr == 0) {
        pS[((long)it * 64 + lr) * 2] = m_run[r];
        pS[((long)it * 64 + lr) * 2 + 1] = l_run[r];
      }
#pragma unroll
      for (int jv = 0; jv < 8; ++jv)
        pO[po + (long)lr * 128 + jv * 16 + fr] = f2b(Oacc[jv][r]);
    }
  }
}

// ---------------- combine partials (log-sum-exp weights) ----------------
__global__ __launch_bounds__(256) void attn_reduce(
    const u16* __restrict__ pO, const float* __restrict__ pS,
    u16* __restrict__ ovb)
{
  const int h = blockIdx.x, qt = blockIdx.y;
  const int ktt = (qt >> 1) + 1;
  const int nkc = (ktt + 3) >> 2;
  int base = 0;
  for (int q = qt + 1; q < 32; ++q) base += nkc_of(q) * 16;
  const int tid = threadIdx.x;
  const int r = tid >> 2, cq = (tid & 3) * 32;

  float m[4], l[4], wgt[4];
  float M = -1e30f;
  for (int i = 0; i < nkc; ++i) {
    const long slot = base + i * 16 + h;
    m[i] = pS[(slot * 64 + r) * 2];
    l[i] = pS[(slot * 64 + r) * 2 + 1];
    M = fmaxf(M, m[i]);
  }
  float L = 0.f;
  for (int i = 0; i < nkc; ++i) { wgt[i] = __expf(m[i] - M); L += l[i] * wgt[i]; }
  const float inv = 1.0f / L;

  u16* orow = ovb + (long)(qt * 64 + r) * 2048 + h * 128 + cq;
  for (int c8 = 0; c8 < 32; c8 += 8) {
    float acc[8] = {};
    for (int i = 0; i < nkc; ++i) {
      const u16x8 v = *(const u16x8*)(pO + ((long)(base + i * 16 + h) * 64 + r) * 128 + cq + c8);
#pragma unroll
      for (int e = 0; e < 8; ++e) acc[e] += b2f(v[e]) * wgt[i];
    }
    u16x8 o;
#pragma unroll
    for (int e = 0; e < 8; ++e) o[e] = f2b(acc[e] * inv);
    *(u16x8*)(orow + c8) = o;
  }
}

// ---------------- conversion / transpose kernels ----------------
__global__ __launch_bounds__(256) void cast_bf16(const float* __restrict__ in,
                                                 u16* __restrict__ out, long n) {
  long i = ((long)blockIdx.x * 256 + threadIdx.x) * 4;
  if (i >= n) return;
  float4 v = *(const float4*)(in + i);
  ushort4 o = { f2b(v.x), f2b(v.y), f2b(v.z), f2b(v.w) };
  *(ushort4*)(out + i) = o;
}

__global__ __launch_bounds__(256) void transpose_cast(const float* __restrict__ in,
    u16* __restrict__ out, int ldi, int ldo, long sIn, long sOut) {
  in += (long)blockIdx.z * sIn;
  out += (long)blockIdx.z * sOut;
  __shared__ u16 t[32][33];
  const int i0 = blockIdx.y * 32, j0 = blockIdx.x * 32;
  const int tx = threadIdx.x & 31, ty = threadIdx.x >> 5;
  for (int r = ty; r < 32; r += 8)
    t[r][tx] = f2b(in[(long)(i0 + r) * ldi + j0 + tx]);
  __syncthreads();
  for (int r = ty; r < 32; r += 8)
    out[(long)(j0 + r) * ldo + i0 + tx] = t[tx][r];
}

// ---------------- RMSNorm fp32 (row stride ldin) -> bf16 ----------------
__global__ __launch_bounds__(256) void rmsnorm_cast(const float* __restrict__ in,
    const float* __restrict__ w, u16* __restrict__ out, int n, int ldin) {
  __shared__ float red[4];
  const float* row = in + (long)blockIdx.x * ldin;
  u16* orow = out + (long)blockIdx.x * n;
  float ss = 0.f;
  for (int i = threadIdx.x; i < n; i += 256) { float v = row[i]; ss += v * v; }
  float tot = block_sum(ss, red);
  float inv = rsqrtf(tot / (float)n + 1e-6f);
  for (int i = threadIdx.x; i < n; i += 256) orow[i] = f2b(row[i] * inv * w[i]);
}

// ---------------- RoPE table (double precision) ----------------
__global__ __launch_bounds__(256) void rope_table(float* tab) {
  int s = blockIdx.x * 8 + (threadIdx.x >> 5), j = threadIdx.x & 31;
  double freq = pow(10000.0, -(double)j / 32.0);
  double ang = (double)s * freq;
  tab[s * 64 + j] = (float)cos(ang);
  tab[s * 64 + 32 + j] = (float)sin(ang);
}

// ---------------- k_full: rmsnorm(ckv) ++ rope(k_pe) -> bf16 ----------------
// ckv points at col 1536 of the fused [2048][2176] f32 buffer.
__global__ __launch_bounds__(256) void build_kfull(const float* __restrict__ ckv,
    const float* __restrict__ lnw, const float* __restrict__ tab, u16* __restrict__ kfb) {
  __shared__ float red[4];
  const int s = blockIdx.x;
  const float* row = ckv + (long)s * 2176;
  float ss = 0.f;
  for (int i = threadIdx.x; i < 512; i += 256) { float v = row[i]; ss += v * v; }
  float tot = block_sum(ss, red);
  float inv = rsqrtf(tot / 512.0f + 1e-6f);
  u16* orow = kfb + (long)s * 576;
  for (int i = threadIdx.x; i < 512; i += 256) orow[i] = f2b(row[i] * inv * lnw[i]);
  if (threadIdx.x < 64) {
    int i = threadIdx.x, j = i & 31;
    float c = tab[s * 64 + j], sn = tab[s * 64 + 32 + j];
    float xv = row[512 + i];
    float rot = (i < 32) ? -row[512 + i + 32] : row[512 + i - 32];
    orow[512 + i] = f2b(xv * c + rot * sn);
  }
}

// ---------------- roped q_pe (bf16 in) into qfb[..., 512:576] ----------------
// grid 2048 x 256 threads: thread (h = t>>4, 4 i's).
__global__ __launch_bounds__(256) void rope_qpe(const u16* __restrict__ qb,
    const float* __restrict__ tab, u16* __restrict__ qfb) {
  const int s = blockIdx.x;
  const int h = threadIdx.x >> 4;
  const int i0 = (threadIdx.x & 15) * 4;
  const u16* src = qb + (long)s * 3072 + h * 192 + 128;
  u16* dst = qfb + (long)s * 9216 + h * 576 + 512;
#pragma unroll
  for (int k = 0; k < 4; ++k) {
    const int i = i0 + k, j = i & 31;
    float c = tab[s * 64 + j], sn = tab[s * 64 + 32 + j];
    float xv = b2f(src[i]);
    float rot = (i < 32) ? -b2f(src[i + 32]) : b2f(src[i - 32]);
    dst[i] = f2b(xv * c + rot * sn);
  }
}

extern "C" void kernel_launch(void* const* d_in, const int* in_sizes, int n_in,
                              void* d_out, int out_size, void* d_ws, size_t ws_size,
                              hipStream_t stream) {
  const float* x      = (const float*)d_in[0];
  const float* w_q_a  = (const float*)d_in[1];
  const float* q_ln   = (const float*)d_in[2];
  const float* w_q_b  = (const float*)d_in[3];
  const float* w_kv_a = (const float*)d_in[4];
  const float* kv_ln  = (const float*)d_in[5];
  const float* w_kv_b = (const float*)d_in[6];
  const float* w_o    = (const float*)d_in[7];
  float* out = (float*)d_out;

  // ---- fixed workspace (bytes) ----
  char* p = (char*)d_ws;
  float* tab   = (float*)p;  p += 524288;      // 2048*64 f32
  u16* wkvbb   = (u16*)p;    p += 4194304;     // 512*4096
  u16* wuvT    = (u16*)p;    p += 2097152;     // 16*128*512
  u16* woT     = (u16*)p;    p += 8388608;     // 2048*2048
  u16* qfb     = (u16*)p;    p += 37748736;    // 2048*9216
  u16* vallT   = (u16*)p;    p += 8388608;     // 16*128*2048
  u16* kfb     = (u16*)p;    p += 2359296;     // 2048*576
  u16* ovb     = (u16*)p;    p += 8388608;     // 2048*2048
  char* tb = p;
  // phase 1 transient:
  u16* xb      = (u16*)tb;                     // 2048*2048            (8.4 MB)
  u16* wabT    = (u16*)(tb + 8388608);         // 2176*2048 (qa++kva transposed)
  float* qac   = (float*)(tb + 17301504);      // 2048*2176 f32 (qa | ckv_kpe)
  u16* qab     = (u16*)(tb + 35127296);        // 2048*1536
  u16* wqbT    = (u16*)(tb + 41418752);        // 3072*1536
  u16* qb      = (u16*)(tb + 50855936);        // 2048*3072  (ends 63.4 MB)
  // phase 2 transient (aliases phase 1, used only after it is dead):
  u16* pO      = (u16*)tb;                     // 1280*64*128 bf16 (21 MB)
  float* pS    = (float*)(tb + 20971520);      // 1280*64*2 f32
  u32* ctr     = (u32*)(tb + 21626880);

  rope_table<<<dim3(256), 256, 0, stream>>>(tab);

  // weight prep
  cast_bf16<<<4096, 256, 0, stream>>>(x, xb, 4194304);
  transpose_cast<<<dim3(48, 64), 256, 0, stream>>>(w_q_a, wabT, 1536, 2048, 0, 0);
  transpose_cast<<<dim3(18, 64), 256, 0, stream>>>(w_kv_a, wabT + 1536 * 2048, 576, 2048, 0, 0);
  transpose_cast<<<dim3(96, 48), 256, 0, stream>>>(w_q_b, wqbT, 3072, 1536, 0, 0);
  cast_bf16<<<2048, 256, 0, stream>>>(w_kv_b, wkvbb, 2097152);
  transpose_cast<<<dim3(4, 16, 16), 256, 0, stream>>>(w_kv_b + 128, wuvT, 4096, 512, 256, 65536);
  transpose_cast<<<dim3(64, 64), 256, 0, stream>>>(w_o, woT, 2048, 2048, 0, 0);

  // fused: [q_a | ckv_kpe] = x @ [w_q_a | w_kv_a]  (f32, ldc 2176)
  gemm_mfma<0><<<dim3(17, 16), 256, 0, stream>>>(
      xb, wabT, qac, 2048, 2048, 2048, 2176, 0, 0, 0);
  rmsnorm_cast<<<2048, 256, 0, stream>>>(qac, q_ln, qab, 1536, 2176);
  build_kfull<<<2048, 256, 0, stream>>>(qac + 1536, kv_ln, tab, kfb);

  // q = q_a @ w_q_b (bf16 out)
  gemm_mfma<1><<<dim3(24, 16), 256, 0, stream>>>(
      qab, wqbT, qb, 1536, 1536, 1536, 3072, 0, 0, 0);

  // q_full[:, h, :512] = q_nope[h] @ w_uk[h]^T (bf16 out, batched over h)
  gemm_mfma<1><<<dim3(4, 16, 16), 256, 0, stream>>>(
      qb, wkvbb, qfb, 128, 3072, 4096, 9216, 192, 256, 576);
  rope_qpe<<<dim3(2048), 256, 0, stream>>>(qb, tab, qfb);

  // vallT[h] = (ckv_n @ w_uv[h])^T  (bf16 transposed out)
  gemm_mfma<2><<<dim3(1, 16, 16), 256, 0, stream>>>(
      kfb, wuvT, vallT, 512, 576, 512, 2048, 0, 65536, 262144);

  // split-K flash attention with dynamic queue
  init_ctr<<<1, 1, 0, stream>>>(ctr);
  attn_partial<<<dim3(512), 256, 0, stream>>>(qfb, kfb, vallT, ctr, pO, pS);
  attn_reduce<<<dim3(16, 32), 256, 0, stream>>>(pO, pS, ovb);

  // y = o_v @ w_o (f32 out)
  gemm_mfma<0><<<dim3(16, 16), 256, 0, stream>>>(
      ovb, woT, out, 2048, 2048, 2048, 2048, 0, 0, 0);
}